// Round 1
// baseline (3779.213 us; speedup 1.0000x reference)
//
#include <hip/hip_runtime.h>
#include <hip/hip_bf16.h>
#include <math.h>

#define V_SIZE 50257
#define V_PAD  50304   // 393*128
#define E_DIM  256
#define H_DIM  512
#define G_DIM  1536
#define B_SZ   4
#define S_LEN  512
#define NTOK   2048

typedef __attribute__((ext_vector_type(8))) short bf16x8;
typedef __attribute__((ext_vector_type(4))) float f32x4;

__device__ __forceinline__ float bf2f(unsigned short u) {
  union { unsigned int i; float f; } x; x.i = ((unsigned int)u) << 16; return x.f;
}
__device__ __forceinline__ unsigned short f2bf(float f) {
  __hip_bfloat16 h = __float2bfloat16(f);   // RNE
  return reinterpret_cast<unsigned short&>(h);
}
__device__ __forceinline__ float sigmoidf_(float x) { return 1.0f / (1.0f + expf(-x)); }

__device__ __forceinline__ void gload_lds16(const void* g, void* l) {
  __builtin_amdgcn_global_load_lds((const __attribute__((address_space(1))) unsigned int*)g,
                                   (__attribute__((address_space(3))) unsigned int*)l, 16, 0, 0);
}

// ---------------- embedding fp32 -> bf16 (padded to V_PAD rows) ----------------
__global__ __launch_bounds__(256) void k_emb2bf(const float* __restrict__ emb,
                                                __hip_bfloat16* __restrict__ out) {
  const long total = (long)V_PAD * E_DIM;
  for (long i = (long)blockIdx.x * 256 + threadIdx.x; i < total; i += (long)gridDim.x * 256) {
    int row = (int)(i >> 8);
    float v = (row < V_SIZE) ? emb[i] : 0.0f;
    out[i] = __float2bfloat16(v);
  }
}

// ---------------- xg = emb[ids] @ W_ih^T + b_ih  (fp32) ----------------
// grid (12, 128), block 256. tile: 128 g x 16 n, K=256
__global__ __launch_bounds__(256) void k_xg(const int* __restrict__ ids, const float* __restrict__ emb,
                                            const float* __restrict__ W_ih, const float* __restrict__ b_ih,
                                            float* __restrict__ xg) {
  __shared__ float embs[16][260];
  __shared__ float wl[64][133];
  const int g0 = blockIdx.x * 128, n0 = blockIdx.y * 16, tid = threadIdx.x;
  for (int idx = tid; idx < 16 * 256; idx += 256) {
    int n = idx >> 8, e = idx & 255;
    embs[n][e] = emb[(long)ids[n0 + n] * E_DIM + e];
  }
  const int g = tid & 127, ng = tid >> 7;
  float acc[8] = {0.f,0.f,0.f,0.f,0.f,0.f,0.f,0.f};
  for (int e0 = 0; e0 < 256; e0 += 64) {
    __syncthreads();
    for (int idx = tid; idx < 128 * 64; idx += 256) {
      int r = idx >> 6, c = idx & 63;
      wl[c][r] = W_ih[(long)(g0 + r) * E_DIM + e0 + c];
    }
    __syncthreads();
    for (int c = 0; c < 64; ++c) {
      float w = wl[c][g];
      #pragma unroll
      for (int j = 0; j < 8; ++j) acc[j] += w * embs[ng * 8 + j][e0 + c];
    }
  }
  const float bias = b_ih[g0 + g];
  #pragma unroll
  for (int j = 0; j < 8; ++j) {
    int n = n0 + ng * 8 + j;
    xg[(long)n * G_DIM + g0 + g] = acc[j] + bias;
  }
}

// ---------------- persistent GRU scan: 32 wgs x 512 thr ----------------
// wg owns h-indices [wg*16, wg*16+16). W_hh slice in LDS (bf16). Cross-wg
// h broadcast via agent-scope release/acquire flags, double-buffered h_buf.
#define NWG 32
__global__ __launch_bounds__(512, 1) void k_scan(const float* __restrict__ xg,
                                                 const float* __restrict__ W_hh,
                                                 const float* __restrict__ b_hh,
                                                 float* __restrict__ states,
                                                 __hip_bfloat16* __restrict__ h_buf,
                                                 int* __restrict__ flags) {
  __shared__ unsigned short Wl[3 * 16 * 520];   // 3 planes [16][520] (pad row 512->520), 49,920 B
  __shared__ float h_lds[512][4];               // 8 KB, [c][b]
  __shared__ float red[8][16][12];              // 6 KB  [wave][i][q*4+b]
  const int wg = blockIdx.x, tid = threadIdx.x;
  const int i0 = wg * 16;
  // stage W slice as bf16 (rows {q*512+i0+i})
  for (int e = tid; e < 3 * 16 * 512; e += 512) {
    int q = e >> 13, i = (e >> 9) & 15, c = e & 511;
    Wl[q * 8320 + i * 520 + c] = f2bf(W_hh[(long)((q << 9) + i0 + i) * H_DIM + c]);
  }
  const int wave = tid >> 6, l = tid & 63, il = l >> 2, part = l & 3;
  const int cb = wave * 64 + part * 16;
  const int ii = tid >> 2, bb = tid & 3;        // epilogue mapping (tid<64)
  float h_prev = 0.0f;
  float bhr = 0.f, bhz = 0.f, bhn = 0.f;
  if (tid < 64) { bhr = b_hh[i0 + ii]; bhz = b_hh[512 + i0 + ii]; bhn = b_hh[1024 + i0 + ii]; }
  __syncthreads();

  for (int t = 0; t < S_LEN; ++t) {
    // prefetch xg for this step (overlaps the spin wait)
    float xr_v = 0.f, xz_v = 0.f, xn_v = 0.f;
    if (tid < 64) {
      const float* xgrow = xg + (long)(bb * S_LEN + t) * G_DIM + i0 + ii;
      xr_v = xgrow[0]; xz_v = xgrow[512]; xn_v = xgrow[1024];
    }
    float acc[3][4] = {{0.f,0.f,0.f,0.f},{0.f,0.f,0.f,0.f},{0.f,0.f,0.f,0.f}};
    if (t > 0) {
      if (tid < 32) {
        while (true) {
          int v = __hip_atomic_load(&flags[tid * 16], __ATOMIC_RELAXED, __HIP_MEMORY_SCOPE_AGENT);
          if (__all(v >= t)) break;
          __builtin_amdgcn_s_sleep(2);
        }
        __builtin_amdgcn_fence(__ATOMIC_ACQUIRE, "agent");
      }
      __syncthreads();
      const __hip_bfloat16* hb = h_buf + ((t - 1) & 1) * (B_SZ * H_DIM);
      for (int e = tid; e < B_SZ * H_DIM; e += 512) {
        int b = e >> 9, c = e & 511;
        h_lds[c][b] = __bfloat162float(hb[e]);
      }
      __syncthreads();
      #pragma unroll
      for (int j = 0; j < 16; j += 2) {
        const int c = cb + j;
        const int base = il * 520 + c;
        ushort2 w_r = *reinterpret_cast<const ushort2*>(&Wl[base]);
        ushort2 w_z = *reinterpret_cast<const ushort2*>(&Wl[8320 + base]);
        ushort2 w_n = *reinterpret_cast<const ushort2*>(&Wl[16640 + base]);
        float4 ha = *reinterpret_cast<const float4*>(&h_lds[c][0]);
        float4 hc = *reinterpret_cast<const float4*>(&h_lds[c + 1][0]);
        float w0[3] = {bf2f(w_r.x), bf2f(w_z.x), bf2f(w_n.x)};
        float w1[3] = {bf2f(w_r.y), bf2f(w_z.y), bf2f(w_n.y)};
        float hv0[4] = {ha.x, ha.y, ha.z, ha.w};
        float hv1[4] = {hc.x, hc.y, hc.z, hc.w};
        #pragma unroll
        for (int q = 0; q < 3; ++q)
          #pragma unroll
          for (int b = 0; b < 4; ++b)
            acc[q][b] += w0[q] * hv0[b] + w1[q] * hv1[b];
      }
    }
    // reduce over 'part' (4 lanes) via butterfly, stash per-wave partials
    #pragma unroll
    for (int q = 0; q < 3; ++q)
      #pragma unroll
      for (int b = 0; b < 4; ++b) {
        float v = acc[q][b];
        v += __shfl_xor(v, 1);
        v += __shfl_xor(v, 2);
        if (part == 0) red[wave][il][q * 4 + b] = v;
      }
    __syncthreads();
    if (tid < 64) {
      float hr = bhr, hz = bhz, hn = bhn;
      #pragma unroll
      for (int w = 0; w < 8; ++w) {
        hr += red[w][ii][0 + bb];
        hz += red[w][ii][4 + bb];
        hn += red[w][ii][8 + bb];
      }
      float r  = sigmoidf_(xr_v + hr);
      float z  = sigmoidf_(xz_v + hz);
      float nn = tanhf(xn_v + r * hn);
      float h_new = (1.0f - z) * nn + z * h_prev;
      h_prev = h_new;
      states[(long)(bb * S_LEN + t) * H_DIM + i0 + ii] = h_new;
      h_buf[(t & 1) * (B_SZ * H_DIM) + bb * H_DIM + i0 + ii] = __float2bfloat16(h_new);
    }
    __syncthreads();   // drains vmcnt for all threads' stores
    if (tid == 0) {
      __hip_atomic_store(&flags[wg * 16], t + 1, __ATOMIC_RELEASE, __HIP_MEMORY_SCOPE_AGENT);
    }
  }
}

// ---------------- read/decay/write gates ----------------
__global__ __launch_bounds__(256) void k_gates(const float* __restrict__ states,
     const float* __restrict__ W_read, const float* __restrict__ b_read,
     const float* __restrict__ W_write, const float* __restrict__ b_write,
     const float* __restrict__ W_decay, const float* __restrict__ b_decay,
     const float* __restrict__ mscale,
     float* __restrict__ read_s, float* __restrict__ decay_s, float* __restrict__ write_s) {
  __shared__ float wr[512], ww[512], wd[512];
  const int tid = threadIdx.x;
  for (int i = tid; i < 512; i += 256) { wr[i] = W_read[i]; ww[i] = W_write[i]; wd[i] = W_decay[i]; }
  __syncthreads();
  const int n = blockIdx.x * 256 + tid;
  const float* st = states + (long)n * H_DIM;
  float ar = 0.f, aw = 0.f, ad = 0.f;
  for (int h = 0; h < 512; ++h) {
    float s = st[h];
    ar += s * wr[h]; aw += s * ww[h]; ad += s * wd[h];
  }
  read_s[n]  = sigmoidf_(ar + b_read[0]) * mscale[0];
  write_s[n] = sigmoidf_(aw + b_write[0]);
  decay_s[n] = sigmoidf_(ad + b_decay[0]);
}

// ---------------- proj = states @ W_he^T + b_he -> bf16 ----------------
// grid (64, 4), block 256. tile 32 n x 64 e, K chunked by 64
__global__ __launch_bounds__(256) void k_proj(const float* __restrict__ states,
                                              const float* __restrict__ W_he,
                                              const float* __restrict__ b_he,
                                              __hip_bfloat16* __restrict__ proj) {
  __shared__ float sts[32][64];
  __shared__ float wle[64][69];
  const int n0 = blockIdx.x * 32, e0 = blockIdx.y * 64, tid = threadIdx.x;
  const int e = tid & 63, ng = tid >> 6;
  float acc[8] = {0.f,0.f,0.f,0.f,0.f,0.f,0.f,0.f};
  for (int h0 = 0; h0 < 512; h0 += 64) {
    __syncthreads();
    for (int idx = tid; idx < 32 * 64; idx += 256) {
      int n = idx >> 6, c = idx & 63;
      sts[n][c] = states[(long)(n0 + n) * H_DIM + h0 + c];
    }
    for (int idx = tid; idx < 64 * 64; idx += 256) {
      int r = idx >> 6, c = idx & 63;
      wle[c][r] = W_he[(long)(e0 + r) * H_DIM + h0 + c];
    }
    __syncthreads();
    for (int c = 0; c < 64; ++c) {
      float w = wle[c][e];
      #pragma unroll
      for (int j = 0; j < 8; ++j) acc[j] += w * sts[ng * 8 + j][c];
    }
  }
  const float bias = b_he[e0 + e];
  #pragma unroll
  for (int j = 0; j < 8; ++j) {
    int n = n0 + ng * 8 + j;
    proj[(long)n * E_DIM + e0 + e] = __float2bfloat16(acc[j] + bias);
  }
}

// ---------------- base = proj @ emb^T + output_bias (bf16 MFMA) ----------------
// grid (393, 16), block 256 (4 waves 2x2), tile 128x128, BK=32, K=256
__global__ __launch_bounds__(256) void k_base(const __hip_bfloat16* __restrict__ A,
                                              const __hip_bfloat16* __restrict__ Bm,
                                              const float* __restrict__ obias,
                                              float* __restrict__ C) {
  __shared__ unsigned short As[128 * 32], Bs[128 * 32];
  const int n0 = blockIdx.x * 128, m0 = blockIdx.y * 128, tid = threadIdx.x;
  const int wid = tid >> 6, l = tid & 63;
  const int wm = wid >> 1, wn = wid & 1;
  f32x4 acc[4][4];
  #pragma unroll
  for (int mi = 0; mi < 4; ++mi)
    #pragma unroll
    for (int ni = 0; ni < 4; ++ni) acc[mi][ni] = (f32x4){0.f, 0.f, 0.f, 0.f};

  for (int kk = 0; kk < 256; kk += 32) {
    __syncthreads();
    #pragma unroll
    for (int s = 0; s < 2; ++s) {
      const int cibase = wid * 128 + s * 64;
      const int ci = cibase + l;
      const int row = ci >> 2, cq = ci & 3;
      gload_lds16(A + (long)(m0 + row) * E_DIM + kk + cq * 8, As + cibase * 8);
      gload_lds16(Bm + (long)(n0 + row) * E_DIM + kk + cq * 8, Bs + cibase * 8);
    }
    __syncthreads();
    bf16x8 af[4], bfr[4];
    const int krow = (l >> 4) * 8;
    #pragma unroll
    for (int mi = 0; mi < 4; ++mi) {
      int row = wm * 64 + mi * 16 + (l & 15);
      af[mi] = *reinterpret_cast<const bf16x8*>(&As[row * 32 + krow]);
    }
    #pragma unroll
    for (int ni = 0; ni < 4; ++ni) {
      int row = wn * 64 + ni * 16 + (l & 15);
      bfr[ni] = *reinterpret_cast<const bf16x8*>(&Bs[row * 32 + krow]);
    }
    #pragma unroll
    for (int mi = 0; mi < 4; ++mi)
      #pragma unroll
      for (int ni = 0; ni < 4; ++ni)
        acc[mi][ni] = __builtin_amdgcn_mfma_f32_16x16x32_bf16(af[mi], bfr[ni], acc[mi][ni], 0, 0, 0);
  }
  #pragma unroll
  for (int mi = 0; mi < 4; ++mi) {
    const int rowb = m0 + wm * 64 + mi * 16 + (l >> 4) * 4;
    #pragma unroll
    for (int ni = 0; ni < 4; ++ni) {
      const int col = n0 + wn * 64 + ni * 16 + (l & 15);
      if (col < V_SIZE) {
        const float ob = obias[col];
        #pragma unroll
        for (int r = 0; r < 4; ++r)
          C[(long)(rowb + r) * V_SIZE + col] = acc[mi][ni][r] + ob;
      }
    }
  }
}

// ---------------- sparse memory correction: out[b,t,v] += read*m ----------------
__global__ __launch_bounds__(256) void k_corr(const int* __restrict__ ids,
                                              const float* __restrict__ read_s,
                                              const float* __restrict__ decay_s,
                                              const float* __restrict__ write_s,
                                              float* __restrict__ out) {
  __shared__ int ids_s[512];
  __shared__ float rd[512], dc[512], wr[512];
  const int b = blockIdx.x, tid = threadIdx.x;
  for (int t = tid; t < 512; t += 256) {
    int n = b * 512 + t;
    ids_s[t] = ids[n]; rd[t] = read_s[n]; dc[t] = decay_s[n]; wr[t] = write_s[n];
  }
  __syncthreads();
  for (int pass = 0; pass < 2; ++pass) {
    const int j = pass * 256 + tid;
    const int v = ids_s[j];
    bool owner = true;
    for (int jj = 0; jj < j; ++jj) if (ids_s[jj] == v) { owner = false; break; }
    if (owner) {
      float m = wr[j];
      float* outb = out + (long)b * S_LEN * V_SIZE + v;
      for (int t = j + 1; t < 512; ++t) {
        outb[(long)t * V_SIZE] += rd[t] * m;
        m *= dc[t];
        if (ids_s[t] == v) m += wr[t];
      }
    }
  }
}

extern "C" void kernel_launch(void* const* d_in, const int* in_sizes, int n_in,
                              void* d_out, int out_size, void* d_ws, size_t ws_size,
                              hipStream_t stream) {
  const int*   ids     = (const int*)d_in[0];
  const float* emb     = (const float*)d_in[1];
  const float* W_ih    = (const float*)d_in[2];
  const float* W_hh    = (const float*)d_in[3];
  const float* b_ih    = (const float*)d_in[4];
  const float* b_hh    = (const float*)d_in[5];
  const float* W_he    = (const float*)d_in[6];
  const float* b_he    = (const float*)d_in[7];
  const float* obias   = (const float*)d_in[8];
  const float* W_read  = (const float*)d_in[9];
  const float* b_read  = (const float*)d_in[10];
  const float* W_write = (const float*)d_in[11];
  const float* b_write = (const float*)d_in[12];
  const float* W_decay = (const float*)d_in[13];
  const float* b_decay = (const float*)d_in[14];
  const float* mscale  = (const float*)d_in[15];

  // ws: emb_bf16 (25.7MB) + proj_bf16 (1MB) + gate scalars (24KB)
  char* ws = (char*)d_ws;
  __hip_bfloat16* emb_bf  = (__hip_bfloat16*)ws;                    // V_PAD*E*2 = 25,755,648
  __hip_bfloat16* proj_bf = (__hip_bfloat16*)(ws + 25755648);       // 1,048,576
  float* read_s  = (float*)(ws + 26804224);
  float* decay_s = (float*)(ws + 26812416);
  float* write_s = (float*)(ws + 26820608);

  // scratch that dies before k_base lives inside d_out (412MB):
  char* ob = (char*)d_out;
  float* xg             = (float*)ob;                  // 12,582,912 B
  float* states         = (float*)(ob + 12582912);     //  4,194,304 B
  __hip_bfloat16* h_buf = (__hip_bfloat16*)(ob + 16777216);  // 8,192 B
  int* flags            = (int*)(ob + 16785408);       // 2,048 B
  float* out            = (float*)d_out;

  hipMemsetAsync(flags, 0, 32 * 16 * sizeof(int), stream);
  k_emb2bf<<<2048, 256, 0, stream>>>(emb, emb_bf);
  dim3 gxg(12, 128);
  k_xg<<<gxg, 256, 0, stream>>>(ids, emb, W_ih, b_ih, xg);
  k_scan<<<NWG, 512, 0, stream>>>(xg, W_hh, b_hh, states, h_buf, flags);
  k_gates<<<8, 256, 0, stream>>>(states, W_read, b_read, W_write, b_write, W_decay, b_decay,
                                 mscale, read_s, decay_s, write_s);
  dim3 gpj(64, 4);
  k_proj<<<gpj, 256, 0, stream>>>(states, W_he, b_he, proj_bf);
  dim3 gb(393, 16);
  k_base<<<gb, 256, 0, stream>>>(proj_bf, emb_bf, obias, out);
  k_corr<<<4, 256, 0, stream>>>(ids, read_s, decay_s, write_s, out);
}

// Round 2
// 2828.374 us; speedup vs baseline: 1.3362x; 1.3362x over previous
//
#include <hip/hip_runtime.h>
#include <hip/hip_bf16.h>
#include <math.h>

#define V_SIZE 50257
#define V_PAD  50304   // 393*128
#define E_DIM  256
#define H_DIM  512
#define G_DIM  1536
#define B_SZ   4
#define S_LEN  512

typedef __attribute__((ext_vector_type(8))) short bf16x8;
typedef __attribute__((ext_vector_type(4))) float f32x4;

__device__ __forceinline__ float bf2f(unsigned short u) {
  union { unsigned int i; float f; } x; x.i = ((unsigned int)u) << 16; return x.f;
}
__device__ __forceinline__ unsigned short f2bf(float f) {
  __hip_bfloat16 h = __float2bfloat16(f);   // RNE
  return reinterpret_cast<unsigned short&>(h);
}
__device__ __forceinline__ float sigmoidf_(float x) { return 1.0f / (1.0f + expf(-x)); }

__device__ __forceinline__ void gload_lds16(const void* g, void* l) {
  __builtin_amdgcn_global_load_lds((const __attribute__((address_space(1))) unsigned int*)g,
                                   (__attribute__((address_space(3))) unsigned int*)l, 16, 0, 0);
}

// ---------------- embedding fp32 -> bf16 (padded to V_PAD rows) ----------------
__global__ __launch_bounds__(256) void k_emb2bf(const float* __restrict__ emb,
                                                __hip_bfloat16* __restrict__ out) {
  const long total = (long)V_PAD * E_DIM;
  for (long i = (long)blockIdx.x * 256 + threadIdx.x; i < total; i += (long)gridDim.x * 256) {
    int row = (int)(i >> 8);
    float v = (row < V_SIZE) ? emb[i] : 0.0f;
    out[i] = __float2bfloat16(v);
  }
}

// ---------------- xg = emb[ids] @ W_ih^T + b_ih  (fp32) ----------------
// grid (12, 128), block 256. tile: 128 g x 16 n, K=256
__global__ __launch_bounds__(256) void k_xg(const int* __restrict__ ids, const float* __restrict__ emb,
                                            const float* __restrict__ W_ih, const float* __restrict__ b_ih,
                                            float* __restrict__ xg) {
  __shared__ float embs[16][260];
  __shared__ float wl[64][133];
  const int g0 = blockIdx.x * 128, n0 = blockIdx.y * 16, tid = threadIdx.x;
  for (int idx = tid; idx < 16 * 256; idx += 256) {
    int n = idx >> 8, e = idx & 255;
    embs[n][e] = emb[(long)ids[n0 + n] * E_DIM + e];
  }
  const int g = tid & 127, ng = tid >> 7;
  float acc[8] = {0.f,0.f,0.f,0.f,0.f,0.f,0.f,0.f};
  for (int e0 = 0; e0 < 256; e0 += 64) {
    __syncthreads();
    for (int idx = tid; idx < 128 * 64; idx += 256) {
      int r = idx >> 6, c = idx & 63;
      wl[c][r] = W_ih[(long)(g0 + r) * E_DIM + e0 + c];
    }
    __syncthreads();
    for (int c = 0; c < 64; ++c) {
      float w = wl[c][g];
      #pragma unroll
      for (int j = 0; j < 8; ++j) acc[j] += w * embs[ng * 8 + j][e0 + c];
    }
  }
  const float bias = b_ih[g0 + g];
  #pragma unroll
  for (int j = 0; j < 8; ++j) {
    int n = n0 + ng * 8 + j;
    xg[(long)n * G_DIM + g0 + g] = acc[j] + bias;
  }
}

// ---------------- persistent GRU scan: 32 wgs x 512 thr ----------------
// Fence-free cross-XCD protocol: all cross-wg data moves via RELAXED
// agent-scope atomics (sc1-coherent, no buffer_inv/wbl2). Writer: data
// atomics -> s_waitcnt vmcnt(0) -> flag atomic. Reader: poll flag -> read.
#define NWG 32
__global__ __launch_bounds__(512, 1) void k_scan(const float* __restrict__ xg,
                                                 const float* __restrict__ W_hh,
                                                 const float* __restrict__ b_hh,
                                                 float* __restrict__ states,
                                                 unsigned int* __restrict__ h_buf,
                                                 int* __restrict__ flags) {
  __shared__ unsigned short Wl[3 * 16 * 520];   // 3 planes [16 rows][520] bf16, 49,920 B
  __shared__ float h2[4][520];                  // [b][c], pad to kill write conflicts
  __shared__ float red[8][16][12];              // [wave][i][q*4+b]
  const int wg = blockIdx.x, tid = threadIdx.x;
  const int i0 = wg * 16;
  for (int e = tid; e < 3 * 16 * 512; e += 512) {
    int q = e >> 13, i = (e >> 9) & 15, c = e & 511;
    Wl[q * 8320 + i * 520 + c] = f2bf(W_hh[(long)((q << 9) + i0 + i) * H_DIM + c]);
  }
  const int wave = tid >> 6, l = tid & 63, il = l >> 2, part = l & 3;
  const int cb = wave * 64 + part * 16;
  const int ii = tid >> 2, bb = tid & 3;        // epilogue mapping (tid<64 == wave 0)
  float h_prev = 0.0f;
  float bhr = 0.f, bhz = 0.f, bhn = 0.f;
  if (tid < 64) { bhr = b_hh[i0 + ii]; bhz = b_hh[512 + i0 + ii]; bhn = b_hh[1024 + i0 + ii]; }
  __syncthreads();

  for (int t = 0; t < S_LEN; ++t) {
    // prefetch xg for this step (overlaps the spin wait)
    float xr_v = 0.f, xz_v = 0.f, xn_v = 0.f;
    if (tid < 64) {
      const float* xgrow = xg + (long)(bb * S_LEN + t) * G_DIM + i0 + ii;
      xr_v = xgrow[0]; xz_v = xgrow[512]; xn_v = xgrow[1024];
    }
    float acc[3][4] = {{0.f,0.f,0.f,0.f},{0.f,0.f,0.f,0.f},{0.f,0.f,0.f,0.f}};
    if (t > 0) {
      if (tid < 32) {
        while (true) {
          int v = __hip_atomic_load(&flags[tid * 16], __ATOMIC_RELAXED, __HIP_MEMORY_SCOPE_AGENT);
          if (__all(v >= t)) break;
          __builtin_amdgcn_s_sleep(1);
        }
      }
      __syncthreads();
      asm volatile("" ::: "memory");
      const unsigned int* hb = h_buf + ((t - 1) & 1) * 1024;
      for (int u = tid; u < 1024; u += 512) {
        unsigned int pv = __hip_atomic_load(&hb[u], __ATOMIC_RELAXED, __HIP_MEMORY_SCOPE_AGENT);
        int b = u >> 8, c = (u & 255) * 2;
        h2[b][c]     = bf2f((unsigned short)(pv & 0xffffu));
        h2[b][c + 1] = bf2f((unsigned short)(pv >> 16));
      }
      __syncthreads();
      #pragma unroll
      for (int j = 0; j < 16; j += 2) {
        const int c = cb + j;
        const int base = il * 520 + c;
        ushort2 w_r = *reinterpret_cast<const ushort2*>(&Wl[base]);
        ushort2 w_z = *reinterpret_cast<const ushort2*>(&Wl[8320 + base]);
        ushort2 w_n = *reinterpret_cast<const ushort2*>(&Wl[16640 + base]);
        float w0[3] = {bf2f(w_r.x), bf2f(w_z.x), bf2f(w_n.x)};
        float w1[3] = {bf2f(w_r.y), bf2f(w_z.y), bf2f(w_n.y)};
        #pragma unroll
        for (int q = 0; q < 3; ++q)
          #pragma unroll
          for (int b = 0; b < 4; ++b)
            acc[q][b] += w0[q] * h2[b][c] + w1[q] * h2[b][c + 1];
      }
    }
    // reduce over 'part' (4 lanes), stash per-wave partials
    #pragma unroll
    for (int q = 0; q < 3; ++q)
      #pragma unroll
      for (int b = 0; b < 4; ++b) {
        float v = acc[q][b];
        v += __shfl_xor(v, 1);
        v += __shfl_xor(v, 2);
        if (part == 0) red[wave][il][q * 4 + b] = v;
      }
    __syncthreads();
    if (tid < 64) {
      float hr = bhr, hz = bhz, hn = bhn;
      #pragma unroll
      for (int w = 0; w < 8; ++w) {
        hr += red[w][ii][0 + bb];
        hz += red[w][ii][4 + bb];
        hn += red[w][ii][8 + bb];
      }
      float r  = sigmoidf_(xr_v + hr);
      float z  = sigmoidf_(xz_v + hz);
      float nn = tanhf(xn_v + r * hn);
      float h_new = (1.0f - z) * nn + z * h_prev;
      h_prev = h_new;
      states[(long)(bb * S_LEN + t) * H_DIM + i0 + ii] = h_new;
      // pack pairs (ii even: {h[ii], h[ii+1]}) and store coherently
      unsigned int mybf = (unsigned int)f2bf(h_new);
      unsigned int other = __shfl_xor(mybf, 4);   // partner row ii^1, same bb
      if ((ii & 1) == 0) {
        unsigned int pk = mybf | (other << 16);
        __hip_atomic_store(&h_buf[(t & 1) * 1024 + bb * 256 + (i0 >> 1) + (ii >> 1)], pk,
                           __ATOMIC_RELAXED, __HIP_MEMORY_SCOPE_AGENT);
      }
      asm volatile("s_waitcnt vmcnt(0)" ::: "memory");   // data at coherence point
      if (tid == 0) {
        __hip_atomic_store(&flags[wg * 16], t + 1, __ATOMIC_RELAXED, __HIP_MEMORY_SCOPE_AGENT);
      }
    }
    // no trailing barrier needed: next iter's poll+fill barriers order red/h2 reuse
  }
}

// ---------------- read/decay/write gates (wave-per-row, coalesced) ----------------
// grid 32, block 256 (4 waves); 2048 rows, 64/block, 16/wave
__global__ __launch_bounds__(256) void k_gates(const float* __restrict__ states,
     const float* __restrict__ W_read, const float* __restrict__ b_read,
     const float* __restrict__ W_write, const float* __restrict__ b_write,
     const float* __restrict__ W_decay, const float* __restrict__ b_decay,
     const float* __restrict__ mscale,
     float* __restrict__ read_s, float* __restrict__ decay_s, float* __restrict__ write_s) {
  __shared__ float wr[512], ww[512], wd[512];
  const int tid = threadIdx.x;
  for (int i = tid; i < 512; i += 256) { wr[i] = W_read[i]; ww[i] = W_write[i]; wd[i] = W_decay[i]; }
  __syncthreads();
  const int wave = tid >> 6, l = tid & 63;
  const float br = b_read[0], bw = b_write[0], bd = b_decay[0], ms = mscale[0];
  for (int r = 0; r < 16; ++r) {
    const int n = blockIdx.x * 64 + wave * 16 + r;
    const float* st = states + (long)n * H_DIM;
    float ar = 0.f, aw = 0.f, ad = 0.f;
    #pragma unroll
    for (int h0 = 0; h0 < 512; h0 += 64) {
      float s = st[h0 + l];
      ar += s * wr[h0 + l]; aw += s * ww[h0 + l]; ad += s * wd[h0 + l];
    }
    #pragma unroll
    for (int k = 1; k < 64; k <<= 1) {
      ar += __shfl_xor(ar, k); aw += __shfl_xor(aw, k); ad += __shfl_xor(ad, k);
    }
    if (l == 0) {
      read_s[n]  = sigmoidf_(ar + br) * ms;
      write_s[n] = sigmoidf_(aw + bw);
      decay_s[n] = sigmoidf_(ad + bd);
    }
  }
}

// ---------------- proj = states @ W_he^T + b_he -> bf16 ----------------
__global__ __launch_bounds__(256) void k_proj(const float* __restrict__ states,
                                              const float* __restrict__ W_he,
                                              const float* __restrict__ b_he,
                                              __hip_bfloat16* __restrict__ proj) {
  __shared__ float sts[32][64];
  __shared__ float wle[64][69];
  const int n0 = blockIdx.x * 32, e0 = blockIdx.y * 64, tid = threadIdx.x;
  const int e = tid & 63, ng = tid >> 6;
  float acc[8] = {0.f,0.f,0.f,0.f,0.f,0.f,0.f,0.f};
  for (int h0 = 0; h0 < 512; h0 += 64) {
    __syncthreads();
    for (int idx = tid; idx < 32 * 64; idx += 256) {
      int n = idx >> 6, c = idx & 63;
      sts[n][c] = states[(long)(n0 + n) * H_DIM + h0 + c];
    }
    for (int idx = tid; idx < 64 * 64; idx += 256) {
      int r = idx >> 6, c = idx & 63;
      wle[c][r] = W_he[(long)(e0 + r) * H_DIM + h0 + c];
    }
    __syncthreads();
    for (int c = 0; c < 64; ++c) {
      float w = wle[c][e];
      #pragma unroll
      for (int j = 0; j < 8; ++j) acc[j] += w * sts[ng * 8 + j][c];
    }
  }
  const float bias = b_he[e0 + e];
  #pragma unroll
  for (int j = 0; j < 8; ++j) {
    int n = n0 + ng * 8 + j;
    proj[(long)n * E_DIM + e0 + e] = __float2bfloat16(acc[j] + bias);
  }
}

// ---------------- base = proj @ emb^T + output_bias (bf16 MFMA) ----------------
// grid (393, 16), block 256 (4 waves 2x2), tile 128x128, BK=32, K=256
__global__ __launch_bounds__(256) void k_base(const __hip_bfloat16* __restrict__ A,
                                              const __hip_bfloat16* __restrict__ Bm,
                                              const float* __restrict__ obias,
                                              float* __restrict__ C) {
  __shared__ unsigned short As[128 * 32], Bs[128 * 32];
  const int n0 = blockIdx.x * 128, m0 = blockIdx.y * 128, tid = threadIdx.x;
  const int wid = tid >> 6, l = tid & 63;
  const int wm = wid >> 1, wn = wid & 1;
  f32x4 acc[4][4];
  #pragma unroll
  for (int mi = 0; mi < 4; ++mi)
    #pragma unroll
    for (int ni = 0; ni < 4; ++ni) acc[mi][ni] = (f32x4){0.f, 0.f, 0.f, 0.f};

  for (int kk = 0; kk < 256; kk += 32) {
    __syncthreads();
    #pragma unroll
    for (int s = 0; s < 2; ++s) {
      const int cibase = wid * 128 + s * 64;
      const int ci = cibase + l;
      const int row = ci >> 2, cq = ci & 3;
      gload_lds16(A + (long)(m0 + row) * E_DIM + kk + cq * 8, As + cibase * 8);
      gload_lds16(Bm + (long)(n0 + row) * E_DIM + kk + cq * 8, Bs + cibase * 8);
    }
    __syncthreads();
    bf16x8 af[4], bfr[4];
    const int krow = (l >> 4) * 8;
    #pragma unroll
    for (int mi = 0; mi < 4; ++mi) {
      int row = wm * 64 + mi * 16 + (l & 15);
      af[mi] = *reinterpret_cast<const bf16x8*>(&As[row * 32 + krow]);
    }
    #pragma unroll
    for (int ni = 0; ni < 4; ++ni) {
      int row = wn * 64 + ni * 16 + (l & 15);
      bfr[ni] = *reinterpret_cast<const bf16x8*>(&Bs[row * 32 + krow]);
    }
    #pragma unroll
    for (int mi = 0; mi < 4; ++mi)
      #pragma unroll
      for (int ni = 0; ni < 4; ++ni)
        acc[mi][ni] = __builtin_amdgcn_mfma_f32_16x16x32_bf16(af[mi], bfr[ni], acc[mi][ni], 0, 0, 0);
  }
  #pragma unroll
  for (int mi = 0; mi < 4; ++mi) {
    const int rowb = m0 + wm * 64 + mi * 16 + (l >> 4) * 4;
    #pragma unroll
    for (int ni = 0; ni < 4; ++ni) {
      const int col = n0 + wn * 64 + ni * 16 + (l & 15);
      if (col < V_SIZE) {
        const float ob = obias[col];
        #pragma unroll
        for (int r = 0; r < 4; ++r)
          C[(long)(rowb + r) * V_SIZE + col] = acc[mi][ni][r] + ob;
      }
    }
  }
}

// ---------------- sparse memory correction: out[b,t,v] += read*m ----------------
// grid (4 batches, 8 owner-chunks) x 64 threads: owner-per-lane, 32 waves total
__global__ __launch_bounds__(64) void k_corr(const int* __restrict__ ids,
                                             const float* __restrict__ read_s,
                                             const float* __restrict__ decay_s,
                                             const float* __restrict__ write_s,
                                             float* __restrict__ out) {
  __shared__ int ids_s[512];
  __shared__ float rd[512], dc[512], wrs[512];
  const int b = blockIdx.x, c = blockIdx.y, l = threadIdx.x;
  for (int t = l; t < 512; t += 64) {
    int n = b * 512 + t;
    ids_s[t] = ids[n]; rd[t] = read_s[n]; dc[t] = decay_s[n]; wrs[t] = write_s[n];
  }
  __syncthreads();
  const int j = c * 64 + l;
  const int v = ids_s[j];
  for (int jj = 0; jj < j; ++jj) if (ids_s[jj] == v) return;  // not the owner
  float m = wrs[j];
  float* outb = out + (long)b * S_LEN * V_SIZE + v;
  for (int t = j + 1; t < 512; ++t) {
    outb[(long)t * V_SIZE] += rd[t] * m;
    m *= dc[t];
    if (ids_s[t] == v) m += wrs[t];
  }
}

extern "C" void kernel_launch(void* const* d_in, const int* in_sizes, int n_in,
                              void* d_out, int out_size, void* d_ws, size_t ws_size,
                              hipStream_t stream) {
  const int*   ids     = (const int*)d_in[0];
  const float* emb     = (const float*)d_in[1];
  const float* W_ih    = (const float*)d_in[2];
  const float* W_hh    = (const float*)d_in[3];
  const float* b_ih    = (const float*)d_in[4];
  const float* b_hh    = (const float*)d_in[5];
  const float* W_he    = (const float*)d_in[6];
  const float* b_he    = (const float*)d_in[7];
  const float* obias   = (const float*)d_in[8];
  const float* W_read  = (const float*)d_in[9];
  const float* b_read  = (const float*)d_in[10];
  const float* W_write = (const float*)d_in[11];
  const float* b_write = (const float*)d_in[12];
  const float* W_decay = (const float*)d_in[13];
  const float* b_decay = (const float*)d_in[14];
  const float* mscale  = (const float*)d_in[15];

  // ws: emb_bf16 (25.7MB) + proj_bf16 (1MB) + gate scalars (24KB)
  char* ws = (char*)d_ws;
  __hip_bfloat16* emb_bf  = (__hip_bfloat16*)ws;                    // V_PAD*E*2 = 25,755,648
  __hip_bfloat16* proj_bf = (__hip_bfloat16*)(ws + 25755648);       // 1,048,576
  float* read_s  = (float*)(ws + 26804224);
  float* decay_s = (float*)(ws + 26812416);
  float* write_s = (float*)(ws + 26820608);

  // scratch that dies before k_base lives inside d_out (412MB):
  char* ob = (char*)d_out;
  float* xg              = (float*)ob;                  // 12,582,912 B
  float* states          = (float*)(ob + 12582912);     //  4,194,304 B
  unsigned int* h_buf    = (unsigned int*)(ob + 16777216);  // 8,192 B
  int* flags             = (int*)(ob + 16785408);       // 2,048 B
  float* out             = (float*)d_out;

  hipMemsetAsync(flags, 0, 32 * 16 * sizeof(int), stream);
  k_emb2bf<<<2048, 256, 0, stream>>>(emb, emb_bf);
  dim3 gxg(12, 128);
  k_xg<<<gxg, 256, 0, stream>>>(ids, emb, W_ih, b_ih, xg);
  k_scan<<<NWG, 512, 0, stream>>>(xg, W_hh, b_hh, states, h_buf, flags);
  k_gates<<<32, 256, 0, stream>>>(states, W_read, b_read, W_write, b_write, W_decay, b_decay,
                                  mscale, read_s, decay_s, write_s);
  dim3 gpj(64, 4);
  k_proj<<<gpj, 256, 0, stream>>>(states, W_he, b_he, proj_bf);
  dim3 gb(393, 16);
  k_base<<<gb, 256, 0, stream>>>(proj_bf, emb_bf, obias, out);
  dim3 gc(4, 8);
  k_corr<<<gc, 64, 0, stream>>>(ids, read_s, decay_s, write_s, out);
}

// Round 3
// 2321.566 us; speedup vs baseline: 1.6279x; 1.2183x over previous
//
#include <hip/hip_runtime.h>
#include <hip/hip_bf16.h>
#include <math.h>

#define V_SIZE 50257
#define V_PAD  50304   // 393*128
#define E_DIM  256
#define H_DIM  512
#define G_DIM  1536
#define B_SZ   4
#define S_LEN  512

typedef __attribute__((ext_vector_type(8))) short bf16x8;
typedef __attribute__((ext_vector_type(4))) float f32x4;

__device__ __forceinline__ float bf2f(unsigned short u) {
  union { unsigned int i; float f; } x; x.i = ((unsigned int)u) << 16; return x.f;
}
__device__ __forceinline__ unsigned short f2bf(float f) {
  __hip_bfloat16 h = __float2bfloat16(f);   // RNE
  return reinterpret_cast<unsigned short&>(h);
}
__device__ __forceinline__ float sigmoidf_(float x) { return 1.0f / (1.0f + expf(-x)); }

__device__ __forceinline__ void gload_lds16(const void* g, void* l) {
  __builtin_amdgcn_global_load_lds((const __attribute__((address_space(1))) unsigned int*)g,
                                   (__attribute__((address_space(3))) unsigned int*)l, 16, 0, 0);
}

// ---------------- embedding fp32 -> bf16 (padded to V_PAD rows) ----------------
__global__ __launch_bounds__(256) void k_emb2bf(const float* __restrict__ emb,
                                                __hip_bfloat16* __restrict__ out) {
  const long total = (long)V_PAD * E_DIM;
  for (long i = (long)blockIdx.x * 256 + threadIdx.x; i < total; i += (long)gridDim.x * 256) {
    int row = (int)(i >> 8);
    float v = (row < V_SIZE) ? emb[i] : 0.0f;
    out[i] = __float2bfloat16(v);
  }
}

// ---------------- xg = emb[ids] @ W_ih^T + b_ih  (fp32) ----------------
// grid (12, 128), block 256. tile: 128 g x 16 n, K=256
__global__ __launch_bounds__(256) void k_xg(const int* __restrict__ ids, const float* __restrict__ emb,
                                            const float* __restrict__ W_ih, const float* __restrict__ b_ih,
                                            float* __restrict__ xg) {
  __shared__ float embs[16][260];
  __shared__ float wl[64][133];
  const int g0 = blockIdx.x * 128, n0 = blockIdx.y * 16, tid = threadIdx.x;
  for (int idx = tid; idx < 16 * 256; idx += 256) {
    int n = idx >> 8, e = idx & 255;
    embs[n][e] = emb[(long)ids[n0 + n] * E_DIM + e];
  }
  const int g = tid & 127, ng = tid >> 7;
  float acc[8] = {0.f,0.f,0.f,0.f,0.f,0.f,0.f,0.f};
  for (int e0 = 0; e0 < 256; e0 += 64) {
    __syncthreads();
    for (int idx = tid; idx < 128 * 64; idx += 256) {
      int r = idx >> 6, c = idx & 63;
      wl[c][r] = W_ih[(long)(g0 + r) * E_DIM + e0 + c];
    }
    __syncthreads();
    for (int c = 0; c < 64; ++c) {
      float w = wl[c][g];
      #pragma unroll
      for (int j = 0; j < 8; ++j) acc[j] += w * embs[ng * 8 + j][e0 + c];
    }
  }
  const float bias = b_ih[g0 + g];
  #pragma unroll
  for (int j = 0; j < 8; ++j) {
    int n = n0 + ng * 8 + j;
    xg[(long)n * G_DIM + g0 + g] = acc[j] + bias;
  }
}

// ---------------- persistent GRU scan: 32 wgs x 512 thr ----------------
// Data-is-the-flag protocol: h for step t is published as fp32 words into
// h_hist[t][2048] (pre-memset to 0xFFFFFFFF = NaN, never a valid h value)
// via RELAXED agent-scope stores. Readers poll the data words themselves
// (no flags, no release ACK). Each wave only needs columns
// [wave*64, wave*64+64), so it polls its own slice into its private LDS
// stripe (same-wave lgkmcnt ordering, no barrier) and starts its MACs
// immediately. One __syncthreads per step (before the wave-0 reduce);
// `red` is double-buffered by t&1 so no trailing barrier is needed.
#define NWG 32
#define WROW 522          // Wl row stride in ushorts (il*5 mod 32 distinct -> 2-way banks)
#define WPLANE (16 * WROW)
__global__ __launch_bounds__(512, 1) void k_scan(const float* __restrict__ xg,
                                                 const float* __restrict__ W_hh,
                                                 const float* __restrict__ b_hh,
                                                 float* __restrict__ states,
                                                 unsigned int* __restrict__ h_hist) {
  __shared__ unsigned short Wl[3 * WPLANE];     // 50,112 B
  __shared__ float hw[8][4][64];                // per-wave h stripe, 8 KB
  __shared__ float red[2][8][16][12];           // double-buffered partials, 12 KB
  const int wg = blockIdx.x, tid = threadIdx.x;
  const int i0 = wg * 16;
  for (int e = tid; e < 3 * 16 * 512; e += 512) {
    int q = e >> 13, i = (e >> 9) & 15, c = e & 511;
    Wl[q * WPLANE + i * WROW + c] = f2bf(W_hh[(long)((q << 9) + i0 + i) * H_DIM + c]);
  }
  const int wave = tid >> 6, l = tid & 63, il = l >> 2, part = l & 3;
  const int ii = tid >> 2, bb = tid & 3;        // epilogue mapping (wave 0)
  float h_prev = 0.0f;
  float bhr = 0.f, bhz = 0.f, bhn = 0.f;
  if (tid < 64) { bhr = b_hh[i0 + ii]; bhz = b_hh[512 + i0 + ii]; bhn = b_hh[1024 + i0 + ii]; }
  __syncthreads();

  for (int t = 0; t < S_LEN; ++t) {
    // xg prefetch for the epilogue (in flight during poll+MAC)
    float xr_v = 0.f, xz_v = 0.f, xn_v = 0.f;
    if (tid < 64) {
      const float* xgrow = xg + (long)(bb * S_LEN + t) * G_DIM + i0 + ii;
      xr_v = xgrow[0]; xz_v = xgrow[512]; xn_v = xgrow[1024];
    }
    float acc[3][4] = {{0.f,0.f,0.f,0.f},{0.f,0.f,0.f,0.f},{0.f,0.f,0.f,0.f}};
    if (t > 0) {
      const unsigned int* hb = h_hist + (long)(t - 1) * 2048;
      const int col = (wave << 6) + l;
      unsigned int v0 = 0xFFFFFFFFu, v1 = 0xFFFFFFFFu, v2 = 0xFFFFFFFFu, v3 = 0xFFFFFFFFu;
      while (true) {
        if (v0 == 0xFFFFFFFFu) v0 = __hip_atomic_load(hb + col,        __ATOMIC_RELAXED, __HIP_MEMORY_SCOPE_AGENT);
        if (v1 == 0xFFFFFFFFu) v1 = __hip_atomic_load(hb + col + 512,  __ATOMIC_RELAXED, __HIP_MEMORY_SCOPE_AGENT);
        if (v2 == 0xFFFFFFFFu) v2 = __hip_atomic_load(hb + col + 1024, __ATOMIC_RELAXED, __HIP_MEMORY_SCOPE_AGENT);
        if (v3 == 0xFFFFFFFFu) v3 = __hip_atomic_load(hb + col + 1536, __ATOMIC_RELAXED, __HIP_MEMORY_SCOPE_AGENT);
        if (v0 != 0xFFFFFFFFu && v1 != 0xFFFFFFFFu && v2 != 0xFFFFFFFFu && v3 != 0xFFFFFFFFu) break;
      }
      union { unsigned int u; float f; } c0, c1, c2, c3;
      c0.u = v0; c1.u = v1; c2.u = v2; c3.u = v3;
      hw[wave][0][l] = c0.f; hw[wave][1][l] = c1.f; hw[wave][2][l] = c2.f; hw[wave][3][l] = c3.f;
      // same-wave LDS RAW: compiler inserts lgkmcnt; no barrier needed
      #pragma unroll
      for (int j = 0; j < 16; j += 2) {
        const int c = part * 16 + j;             // local column within wave stripe
        const int base = il * WROW + (wave << 6) + c;
        ushort2 w_r = *reinterpret_cast<const ushort2*>(&Wl[base]);
        ushort2 w_z = *reinterpret_cast<const ushort2*>(&Wl[WPLANE + base]);
        ushort2 w_n = *reinterpret_cast<const ushort2*>(&Wl[2 * WPLANE + base]);
        float w0[3] = {bf2f(w_r.x), bf2f(w_z.x), bf2f(w_n.x)};
        float w1[3] = {bf2f(w_r.y), bf2f(w_z.y), bf2f(w_n.y)};
        #pragma unroll
        for (int b = 0; b < 4; ++b) {
          float2 hv = *reinterpret_cast<const float2*>(&hw[wave][b][c]);
          #pragma unroll
          for (int q = 0; q < 3; ++q)
            acc[q][b] += w0[q] * hv.x + w1[q] * hv.y;
        }
      }
    }
    // reduce over 'part' (4 lanes), stash per-wave partials
    #pragma unroll
    for (int q = 0; q < 3; ++q)
      #pragma unroll
      for (int b = 0; b < 4; ++b) {
        float v = acc[q][b];
        v += __shfl_xor(v, 1);
        v += __shfl_xor(v, 2);
        if (part == 0) red[t & 1][wave][il][q * 4 + b] = v;
      }
    __syncthreads();                             // the ONE barrier per step
    if (tid < 64) {
      float hr = bhr, hz = bhz, hn = bhn;
      #pragma unroll
      for (int w = 0; w < 8; ++w) {
        hr += red[t & 1][w][ii][0 + bb];
        hz += red[t & 1][w][ii][4 + bb];
        hn += red[t & 1][w][ii][8 + bb];
      }
      float r  = sigmoidf_(xr_v + hr);
      float z  = sigmoidf_(xz_v + hz);
      float nn = tanhf(xn_v + r * hn);
      float h_new = (1.0f - z) * nn + z * h_prev;
      h_prev = h_new;
      union { float f; unsigned int u; } pv; pv.f = h_new;
      __hip_atomic_store(h_hist + (long)t * 2048 + bb * 512 + i0 + ii, pv.u,
                         __ATOMIC_RELAXED, __HIP_MEMORY_SCOPE_AGENT);
      states[(long)(bb * S_LEN + t) * H_DIM + i0 + ii] = h_new;
    }
    // no trailing barrier: hw is per-wave, red double-buffered, epilogue wave0-local
  }
}

// ---------------- read/decay/write gates (wave-per-row, coalesced) ----------------
__global__ __launch_bounds__(256) void k_gates(const float* __restrict__ states,
     const float* __restrict__ W_read, const float* __restrict__ b_read,
     const float* __restrict__ W_write, const float* __restrict__ b_write,
     const float* __restrict__ W_decay, const float* __restrict__ b_decay,
     const float* __restrict__ mscale,
     float* __restrict__ read_s, float* __restrict__ decay_s, float* __restrict__ write_s) {
  __shared__ float wr[512], ww[512], wd[512];
  const int tid = threadIdx.x;
  for (int i = tid; i < 512; i += 256) { wr[i] = W_read[i]; ww[i] = W_write[i]; wd[i] = W_decay[i]; }
  __syncthreads();
  const int wave = tid >> 6, l = tid & 63;
  const float br = b_read[0], bw = b_write[0], bd = b_decay[0], ms = mscale[0];
  for (int r = 0; r < 16; ++r) {
    const int n = blockIdx.x * 64 + wave * 16 + r;
    const float* st = states + (long)n * H_DIM;
    float ar = 0.f, aw = 0.f, ad = 0.f;
    #pragma unroll
    for (int h0 = 0; h0 < 512; h0 += 64) {
      float s = st[h0 + l];
      ar += s * wr[h0 + l]; aw += s * ww[h0 + l]; ad += s * wd[h0 + l];
    }
    #pragma unroll
    for (int k = 1; k < 64; k <<= 1) {
      ar += __shfl_xor(ar, k); aw += __shfl_xor(aw, k); ad += __shfl_xor(ad, k);
    }
    if (l == 0) {
      read_s[n]  = sigmoidf_(ar + br) * ms;
      write_s[n] = sigmoidf_(aw + bw);
      decay_s[n] = sigmoidf_(ad + bd);
    }
  }
}

// ---------------- proj = states @ W_he^T + b_he -> bf16 ----------------
__global__ __launch_bounds__(256) void k_proj(const float* __restrict__ states,
                                              const float* __restrict__ W_he,
                                              const float* __restrict__ b_he,
                                              __hip_bfloat16* __restrict__ proj) {
  __shared__ float sts[32][64];
  __shared__ float wle[64][69];
  const int n0 = blockIdx.x * 32, e0 = blockIdx.y * 64, tid = threadIdx.x;
  const int e = tid & 63, ng = tid >> 6;
  float acc[8] = {0.f,0.f,0.f,0.f,0.f,0.f,0.f,0.f};
  for (int h0 = 0; h0 < 512; h0 += 64) {
    __syncthreads();
    for (int idx = tid; idx < 32 * 64; idx += 256) {
      int n = idx >> 6, c = idx & 63;
      sts[n][c] = states[(long)(n0 + n) * H_DIM + h0 + c];
    }
    for (int idx = tid; idx < 64 * 64; idx += 256) {
      int r = idx >> 6, c = idx & 63;
      wle[c][r] = W_he[(long)(e0 + r) * H_DIM + h0 + c];
    }
    __syncthreads();
    for (int c = 0; c < 64; ++c) {
      float w = wle[c][e];
      #pragma unroll
      for (int j = 0; j < 8; ++j) acc[j] += w * sts[ng * 8 + j][c];
    }
  }
  const float bias = b_he[e0 + e];
  #pragma unroll
  for (int j = 0; j < 8; ++j) {
    int n = n0 + ng * 8 + j;
    proj[(long)n * E_DIM + e0 + e] = __float2bfloat16(acc[j] + bias);
  }
}

// ---------------- base = proj @ emb^T + output_bias (bf16 MFMA) ----------------
// grid (393, 16), block 256 (4 waves 2x2), tile 128x128, BK=32, K=256
__global__ __launch_bounds__(256) void k_base(const __hip_bfloat16* __restrict__ A,
                                              const __hip_bfloat16* __restrict__ Bm,
                                              const float* __restrict__ obias,
                                              float* __restrict__ C) {
  __shared__ unsigned short As[128 * 32], Bs[128 * 32];
  const int n0 = blockIdx.x * 128, m0 = blockIdx.y * 128, tid = threadIdx.x;
  const int wid = tid >> 6, l = tid & 63;
  const int wm = wid >> 1, wn = wid & 1;
  f32x4 acc[4][4];
  #pragma unroll
  for (int mi = 0; mi < 4; ++mi)
    #pragma unroll
    for (int ni = 0; ni < 4; ++ni) acc[mi][ni] = (f32x4){0.f, 0.f, 0.f, 0.f};

  for (int kk = 0; kk < 256; kk += 32) {
    __syncthreads();
    #pragma unroll
    for (int s = 0; s < 2; ++s) {
      const int cibase = wid * 128 + s * 64;
      const int ci = cibase + l;
      const int row = ci >> 2, cq = ci & 3;
      gload_lds16(A + (long)(m0 + row) * E_DIM + kk + cq * 8, As + cibase * 8);
      gload_lds16(Bm + (long)(n0 + row) * E_DIM + kk + cq * 8, Bs + cibase * 8);
    }
    __syncthreads();
    bf16x8 af[4], bfr[4];
    const int krow = (l >> 4) * 8;
    #pragma unroll
    for (int mi = 0; mi < 4; ++mi) {
      int row = wm * 64 + mi * 16 + (l & 15);
      af[mi] = *reinterpret_cast<const bf16x8*>(&As[row * 32 + krow]);
    }
    #pragma unroll
    for (int ni = 0; ni < 4; ++ni) {
      int row = wn * 64 + ni * 16 + (l & 15);
      bfr[ni] = *reinterpret_cast<const bf16x8*>(&Bs[row * 32 + krow]);
    }
    #pragma unroll
    for (int mi = 0; mi < 4; ++mi)
      #pragma unroll
      for (int ni = 0; ni < 4; ++ni)
        acc[mi][ni] = __builtin_amdgcn_mfma_f32_16x16x32_bf16(af[mi], bfr[ni], acc[mi][ni], 0, 0, 0);
  }
  #pragma unroll
  for (int mi = 0; mi < 4; ++mi) {
    const int rowb = m0 + wm * 64 + mi * 16 + (l >> 4) * 4;
    #pragma unroll
    for (int ni = 0; ni < 4; ++ni) {
      const int col = n0 + wn * 64 + ni * 16 + (l & 15);
      if (col < V_SIZE) {
        const float ob = obias[col];
        #pragma unroll
        for (int r = 0; r < 4; ++r)
          C[(long)(rowb + r) * V_SIZE + col] = acc[mi][ni][r] + ob;
      }
    }
  }
}

// ---------------- sparse memory correction: out[b,t,v] += read*m ----------------
// grid (4 batches, 8 owner-chunks) x 64 threads: owner-per-lane
__global__ __launch_bounds__(64) void k_corr(const int* __restrict__ ids,
                                             const float* __restrict__ read_s,
                                             const float* __restrict__ decay_s,
                                             const float* __restrict__ write_s,
                                             float* __restrict__ out) {
  __shared__ int ids_s[512];
  __shared__ float rd[512], dc[512], wrs[512];
  const int b = blockIdx.x, c = blockIdx.y, l = threadIdx.x;
  for (int t = l; t < 512; t += 64) {
    int n = b * 512 + t;
    ids_s[t] = ids[n]; rd[t] = read_s[n]; dc[t] = decay_s[n]; wrs[t] = write_s[n];
  }
  __syncthreads();
  const int j = c * 64 + l;
  const int v = ids_s[j];
  for (int jj = 0; jj < j; ++jj) if (ids_s[jj] == v) return;  // not the owner
  float m = wrs[j];
  float* outb = out + (long)b * S_LEN * V_SIZE + v;
  for (int t = j + 1; t < 512; ++t) {
    outb[(long)t * V_SIZE] += rd[t] * m;
    m *= dc[t];
    if (ids_s[t] == v) m += wrs[t];
  }
}

extern "C" void kernel_launch(void* const* d_in, const int* in_sizes, int n_in,
                              void* d_out, int out_size, void* d_ws, size_t ws_size,
                              hipStream_t stream) {
  const int*   ids     = (const int*)d_in[0];
  const float* emb     = (const float*)d_in[1];
  const float* W_ih    = (const float*)d_in[2];
  const float* W_hh    = (const float*)d_in[3];
  const float* b_ih    = (const float*)d_in[4];
  const float* b_hh    = (const float*)d_in[5];
  const float* W_he    = (const float*)d_in[6];
  const float* b_he    = (const float*)d_in[7];
  const float* obias   = (const float*)d_in[8];
  const float* W_read  = (const float*)d_in[9];
  const float* b_read  = (const float*)d_in[10];
  const float* W_write = (const float*)d_in[11];
  const float* b_write = (const float*)d_in[12];
  const float* W_decay = (const float*)d_in[13];
  const float* b_decay = (const float*)d_in[14];
  const float* mscale  = (const float*)d_in[15];

  // ws: emb_bf16 (25.7MB) + proj_bf16 (1MB) + gate scalars (24KB)
  char* ws = (char*)d_ws;
  __hip_bfloat16* emb_bf  = (__hip_bfloat16*)ws;                    // V_PAD*E*2 = 25,755,648
  __hip_bfloat16* proj_bf = (__hip_bfloat16*)(ws + 25755648);       // 1,048,576
  float* read_s  = (float*)(ws + 26804224);
  float* decay_s = (float*)(ws + 26812416);
  float* write_s = (float*)(ws + 26820608);

  // scratch that dies before k_base lives inside d_out (412MB):
  char* ob = (char*)d_out;
  float* xg           = (float*)ob;                     // 12,582,912 B
  float* states       = (float*)(ob + 12582912);        //  4,194,304 B
  unsigned int* h_hist = (unsigned int*)(ob + 16777216); // 512*2048*4 = 4,194,304 B
  float* out          = (float*)d_out;

  hipMemsetAsync(h_hist, 0xFF, (size_t)S_LEN * 2048 * sizeof(unsigned int), stream);
  k_emb2bf<<<2048, 256, 0, stream>>>(emb, emb_bf);
  dim3 gxg(12, 128);
  k_xg<<<gxg, 256, 0, stream>>>(ids, emb, W_ih, b_ih, xg);
  k_scan<<<NWG, 512, 0, stream>>>(xg, W_hh, b_hh, states, h_hist);
  k_gates<<<32, 256, 0, stream>>>(states, W_read, b_read, W_write, b_write, W_decay, b_decay,
                                  mscale, read_s, decay_s, write_s);
  dim3 gpj(64, 4);
  k_proj<<<gpj, 256, 0, stream>>>(states, W_he, b_he, proj_bf);
  dim3 gb(393, 16);
  k_base<<<gb, 256, 0, stream>>>(proj_bf, emb_bf, obias, out);
  dim3 gc(4, 8);
  k_corr<<<gc, 64, 0, stream>>>(ids, read_s, decay_s, write_s, out);
}

// Round 4
// 2259.306 us; speedup vs baseline: 1.6727x; 1.0276x over previous
//
#include <hip/hip_runtime.h>
#include <hip/hip_bf16.h>
#include <math.h>

#define V_SIZE 50257
#define V_PAD  50304   // 393*128
#define E_DIM  256
#define H_DIM  512
#define G_DIM  1536
#define B_SZ   4
#define S_LEN  512

typedef __attribute__((ext_vector_type(8))) short bf16x8;
typedef __attribute__((ext_vector_type(4))) float f32x4;

__device__ __forceinline__ float bf2f(unsigned short u) {
  union { unsigned int i; float f; } x; x.i = ((unsigned int)u) << 16; return x.f;
}
__device__ __forceinline__ unsigned short f2bf(float f) {
  __hip_bfloat16 h = __float2bfloat16(f);   // RNE
  return reinterpret_cast<unsigned short&>(h);
}
__device__ __forceinline__ float sigmoidf_(float x) { return 1.0f / (1.0f + expf(-x)); }
// fast variants for the scan's serial epilogue (err ~1e-7 rel, threshold is 2e-2)
__device__ __forceinline__ float fsig(float x) { return 1.0f / (1.0f + __expf(-x)); }
__device__ __forceinline__ float ftanh(float x) { return 1.0f - 2.0f / (__expf(2.0f * x) + 1.0f); }

__device__ __forceinline__ void gload_lds16(const void* g, void* l) {
  __builtin_amdgcn_global_load_lds((const __attribute__((address_space(1))) unsigned int*)g,
                                   (__attribute__((address_space(3))) unsigned int*)l, 16, 0, 0);
}

// ---------------- embedding fp32 -> bf16 (padded to V_PAD rows) ----------------
__global__ __launch_bounds__(256) void k_emb2bf(const float* __restrict__ emb,
                                                __hip_bfloat16* __restrict__ out) {
  const long total = (long)V_PAD * E_DIM;
  for (long i = (long)blockIdx.x * 256 + threadIdx.x; i < total; i += (long)gridDim.x * 256) {
    int row = (int)(i >> 8);
    float v = (row < V_SIZE) ? emb[i] : 0.0f;
    out[i] = __float2bfloat16(v);
  }
}

// ---------------- xg = emb[ids] @ W_ih^T + b_ih  (fp32) ----------------
// grid (12, 128), block 256. tile: 128 g x 16 n, K=256
__global__ __launch_bounds__(256) void k_xg(const int* __restrict__ ids, const float* __restrict__ emb,
                                            const float* __restrict__ W_ih, const float* __restrict__ b_ih,
                                            float* __restrict__ xg) {
  __shared__ float embs[16][260];
  __shared__ float wl[64][133];
  const int g0 = blockIdx.x * 128, n0 = blockIdx.y * 16, tid = threadIdx.x;
  for (int idx = tid; idx < 16 * 256; idx += 256) {
    int n = idx >> 8, e = idx & 255;
    embs[n][e] = emb[(long)ids[n0 + n] * E_DIM + e];
  }
  const int g = tid & 127, ng = tid >> 7;
  float acc[8] = {0.f,0.f,0.f,0.f,0.f,0.f,0.f,0.f};
  for (int e0 = 0; e0 < 256; e0 += 64) {
    __syncthreads();
    for (int idx = tid; idx < 128 * 64; idx += 256) {
      int r = idx >> 6, c = idx & 63;
      wl[c][r] = W_ih[(long)(g0 + r) * E_DIM + e0 + c];
    }
    __syncthreads();
    for (int c = 0; c < 64; ++c) {
      float w = wl[c][g];
      #pragma unroll
      for (int j = 0; j < 8; ++j) acc[j] += w * embs[ng * 8 + j][e0 + c];
    }
  }
  const float bias = b_ih[g0 + g];
  #pragma unroll
  for (int j = 0; j < 8; ++j) {
    int n = n0 + ng * 8 + j;
    xg[(long)n * G_DIM + g0 + g] = acc[j] + bias;
  }
}

// ---------------- persistent GRU scan: 32 wgs x 512 thr ----------------
// Data-is-the-flag protocol (see R3). R4: branchless poll — all 4 agent-scope
// loads issue back-to-back each iteration (single vmcnt wait, ~1 MALL round
// trip per poll iter instead of up to 4 serialized ones).
#define NWG 32
#define WROW 522          // Wl row stride in ushorts (il*5 mod 32 distinct -> 2-way banks)
#define WPLANE (16 * WROW)
__global__ __launch_bounds__(512, 1) void k_scan(const float* __restrict__ xg,
                                                 const float* __restrict__ W_hh,
                                                 const float* __restrict__ b_hh,
                                                 float* __restrict__ states,
                                                 unsigned int* __restrict__ h_hist) {
  __shared__ unsigned short Wl[3 * WPLANE];     // 50,112 B
  __shared__ float hw[8][4][64];                // per-wave h stripe, 8 KB
  __shared__ float red[2][8][16][12];           // double-buffered partials, 12 KB
  const int wg = blockIdx.x, tid = threadIdx.x;
  const int i0 = wg * 16;
  for (int e = tid; e < 3 * 16 * 512; e += 512) {
    int q = e >> 13, i = (e >> 9) & 15, c = e & 511;
    Wl[q * WPLANE + i * WROW + c] = f2bf(W_hh[(long)((q << 9) + i0 + i) * H_DIM + c]);
  }
  const int wave = tid >> 6, l = tid & 63, il = l >> 2, part = l & 3;
  const int ii = tid >> 2, bb = tid & 3;        // epilogue mapping (wave 0)
  float h_prev = 0.0f;
  float bhr = 0.f, bhz = 0.f, bhn = 0.f;
  if (tid < 64) { bhr = b_hh[i0 + ii]; bhz = b_hh[512 + i0 + ii]; bhn = b_hh[1024 + i0 + ii]; }
  __syncthreads();

  for (int t = 0; t < S_LEN; ++t) {
    // xg prefetch for the epilogue (in flight during poll+MAC)
    float xr_v = 0.f, xz_v = 0.f, xn_v = 0.f;
    if (tid < 64) {
      const float* xgrow = xg + (long)(bb * S_LEN + t) * G_DIM + i0 + ii;
      xr_v = xgrow[0]; xz_v = xgrow[512]; xn_v = xgrow[1024];
    }
    float acc[3][4] = {{0.f,0.f,0.f,0.f},{0.f,0.f,0.f,0.f},{0.f,0.f,0.f,0.f}};
    if (t > 0) {
      const unsigned int* hb = h_hist + (long)(t - 1) * 2048;
      const int col = (wave << 6) + l;
      unsigned int v0, v1, v2, v3;
      do {      // branchless: 4 loads in flight together, one wait, one check
        v0 = __hip_atomic_load(hb + col,        __ATOMIC_RELAXED, __HIP_MEMORY_SCOPE_AGENT);
        v1 = __hip_atomic_load(hb + col + 512,  __ATOMIC_RELAXED, __HIP_MEMORY_SCOPE_AGENT);
        v2 = __hip_atomic_load(hb + col + 1024, __ATOMIC_RELAXED, __HIP_MEMORY_SCOPE_AGENT);
        v3 = __hip_atomic_load(hb + col + 1536, __ATOMIC_RELAXED, __HIP_MEMORY_SCOPE_AGENT);
      } while (v0 == 0xFFFFFFFFu || v1 == 0xFFFFFFFFu ||
               v2 == 0xFFFFFFFFu || v3 == 0xFFFFFFFFu);
      union { unsigned int u; float f; } c0, c1, c2, c3;
      c0.u = v0; c1.u = v1; c2.u = v2; c3.u = v3;
      hw[wave][0][l] = c0.f; hw[wave][1][l] = c1.f; hw[wave][2][l] = c2.f; hw[wave][3][l] = c3.f;
      // same-wave LDS RAW: wave-synchronous, no barrier needed
      #pragma unroll
      for (int j = 0; j < 16; j += 2) {
        const int c = part * 16 + j;             // local column within wave stripe
        const int base = il * WROW + (wave << 6) + c;
        ushort2 w_r = *reinterpret_cast<const ushort2*>(&Wl[base]);
        ushort2 w_z = *reinterpret_cast<const ushort2*>(&Wl[WPLANE + base]);
        ushort2 w_n = *reinterpret_cast<const ushort2*>(&Wl[2 * WPLANE + base]);
        float w0[3] = {bf2f(w_r.x), bf2f(w_z.x), bf2f(w_n.x)};
        float w1[3] = {bf2f(w_r.y), bf2f(w_z.y), bf2f(w_n.y)};
        #pragma unroll
        for (int b = 0; b < 4; ++b) {
          float2 hv = *reinterpret_cast<const float2*>(&hw[wave][b][c]);
          #pragma unroll
          for (int q = 0; q < 3; ++q)
            acc[q][b] += w0[q] * hv.x + w1[q] * hv.y;
        }
      }
    }
    // reduce over 'part' (4 lanes), stash per-wave partials
    #pragma unroll
    for (int q = 0; q < 3; ++q)
      #pragma unroll
      for (int b = 0; b < 4; ++b) {
        float v = acc[q][b];
        v += __shfl_xor(v, 1);
        v += __shfl_xor(v, 2);
        if (part == 0) red[t & 1][wave][il][q * 4 + b] = v;
      }
    __syncthreads();                             // the ONE barrier per step
    if (tid < 64) {
      float hr = bhr, hz = bhz, hn = bhn;
      #pragma unroll
      for (int w = 0; w < 8; ++w) {
        hr += red[t & 1][w][ii][0 + bb];
        hz += red[t & 1][w][ii][4 + bb];
        hn += red[t & 1][w][ii][8 + bb];
      }
      float r  = fsig(xr_v + hr);
      float z  = fsig(xz_v + hz);
      float nn = ftanh(xn_v + r * hn);
      float h_new = (1.0f - z) * nn + z * h_prev;
      h_prev = h_new;
      union { float f; unsigned int u; } pv; pv.f = h_new;
      __hip_atomic_store(h_hist + (long)t * 2048 + bb * 512 + i0 + ii, pv.u,
                         __ATOMIC_RELAXED, __HIP_MEMORY_SCOPE_AGENT);
      states[(long)(bb * S_LEN + t) * H_DIM + i0 + ii] = h_new;
    }
    // no trailing barrier: hw per-wave, red double-buffered, epilogue wave0-local
  }
}

// ---------------- read/decay/write gates (wave-per-row, coalesced) ----------------
__global__ __launch_bounds__(256) void k_gates(const float* __restrict__ states,
     const float* __restrict__ W_read, const float* __restrict__ b_read,
     const float* __restrict__ W_write, const float* __restrict__ b_write,
     const float* __restrict__ W_decay, const float* __restrict__ b_decay,
     const float* __restrict__ mscale,
     float* __restrict__ read_s, float* __restrict__ decay_s, float* __restrict__ write_s) {
  __shared__ float wr[512], ww[512], wd[512];
  const int tid = threadIdx.x;
  for (int i = tid; i < 512; i += 256) { wr[i] = W_read[i]; ww[i] = W_write[i]; wd[i] = W_decay[i]; }
  __syncthreads();
  const int wave = tid >> 6, l = tid & 63;
  const float br = b_read[0], bw = b_write[0], bd = b_decay[0], ms = mscale[0];
  for (int r = 0; r < 16; ++r) {
    const int n = blockIdx.x * 64 + wave * 16 + r;
    const float* st = states + (long)n * H_DIM;
    float ar = 0.f, aw = 0.f, ad = 0.f;
    #pragma unroll
    for (int h0 = 0; h0 < 512; h0 += 64) {
      float s = st[h0 + l];
      ar += s * wr[h0 + l]; aw += s * ww[h0 + l]; ad += s * wd[h0 + l];
    }
    #pragma unroll
    for (int k = 1; k < 64; k <<= 1) {
      ar += __shfl_xor(ar, k); aw += __shfl_xor(aw, k); ad += __shfl_xor(ad, k);
    }
    if (l == 0) {
      read_s[n]  = sigmoidf_(ar + br) * ms;
      write_s[n] = sigmoidf_(aw + bw);
      decay_s[n] = sigmoidf_(ad + bd);
    }
  }
}

// ---------------- proj = states @ W_he^T + b_he -> bf16 ----------------
__global__ __launch_bounds__(256) void k_proj(const float* __restrict__ states,
                                              const float* __restrict__ W_he,
                                              const float* __restrict__ b_he,
                                              __hip_bfloat16* __restrict__ proj) {
  __shared__ float sts[32][64];
  __shared__ float wle[64][69];
  const int n0 = blockIdx.x * 32, e0 = blockIdx.y * 64, tid = threadIdx.x;
  const int e = tid & 63, ng = tid >> 6;
  float acc[8] = {0.f,0.f,0.f,0.f,0.f,0.f,0.f,0.f};
  for (int h0 = 0; h0 < 512; h0 += 64) {
    __syncthreads();
    for (int idx = tid; idx < 32 * 64; idx += 256) {
      int n = idx >> 6, c = idx & 63;
      sts[n][c] = states[(long)(n0 + n) * H_DIM + h0 + c];
    }
    for (int idx = tid; idx < 64 * 64; idx += 256) {
      int r = idx >> 6, c = idx & 63;
      wle[c][r] = W_he[(long)(e0 + r) * H_DIM + h0 + c];
    }
    __syncthreads();
    for (int c = 0; c < 64; ++c) {
      float w = wle[c][e];
      #pragma unroll
      for (int j = 0; j < 8; ++j) acc[j] += w * sts[ng * 8 + j][c];
    }
  }
  const float bias = b_he[e0 + e];
  #pragma unroll
  for (int j = 0; j < 8; ++j) {
    int n = n0 + ng * 8 + j;
    proj[(long)n * E_DIM + e0 + e] = __float2bfloat16(acc[j] + bias);
  }
}

// ---------------- base = proj @ emb^T + output_bias (bf16 MFMA) ----------------
// grid (393, 16), block 256 (4 waves 2x2), tile 128x128, BK=32, K=256
__global__ __launch_bounds__(256) void k_base(const __hip_bfloat16* __restrict__ A,
                                              const __hip_bfloat16* __restrict__ Bm,
                                              const float* __restrict__ obias,
                                              float* __restrict__ C) {
  __shared__ unsigned short As[128 * 32], Bs[128 * 32];
  const int n0 = blockIdx.x * 128, m0 = blockIdx.y * 128, tid = threadIdx.x;
  const int wid = tid >> 6, l = tid & 63;
  const int wm = wid >> 1, wn = wid & 1;
  f32x4 acc[4][4];
  #pragma unroll
  for (int mi = 0; mi < 4; ++mi)
    #pragma unroll
    for (int ni = 0; ni < 4; ++ni) acc[mi][ni] = (f32x4){0.f, 0.f, 0.f, 0.f};

  for (int kk = 0; kk < 256; kk += 32) {
    __syncthreads();
    #pragma unroll
    for (int s = 0; s < 2; ++s) {
      const int cibase = wid * 128 + s * 64;
      const int ci = cibase + l;
      const int row = ci >> 2, cq = ci & 3;
      gload_lds16(A + (long)(m0 + row) * E_DIM + kk + cq * 8, As + cibase * 8);
      gload_lds16(Bm + (long)(n0 + row) * E_DIM + kk + cq * 8, Bs + cibase * 8);
    }
    __syncthreads();
    bf16x8 af[4], bfr[4];
    const int krow = (l >> 4) * 8;
    #pragma unroll
    for (int mi = 0; mi < 4; ++mi) {
      int row = wm * 64 + mi * 16 + (l & 15);
      af[mi] = *reinterpret_cast<const bf16x8*>(&As[row * 32 + krow]);
    }
    #pragma unroll
    for (int ni = 0; ni < 4; ++ni) {
      int row = wn * 64 + ni * 16 + (l & 15);
      bfr[ni] = *reinterpret_cast<const bf16x8*>(&Bs[row * 32 + krow]);
    }
    #pragma unroll
    for (int mi = 0; mi < 4; ++mi)
      #pragma unroll
      for (int ni = 0; ni < 4; ++ni)
        acc[mi][ni] = __builtin_amdgcn_mfma_f32_16x16x32_bf16(af[mi], bfr[ni], acc[mi][ni], 0, 0, 0);
  }
  #pragma unroll
  for (int mi = 0; mi < 4; ++mi) {
    const int rowb = m0 + wm * 64 + mi * 16 + (l >> 4) * 4;
    #pragma unroll
    for (int ni = 0; ni < 4; ++ni) {
      const int col = n0 + wn * 64 + ni * 16 + (l & 15);
      if (col < V_SIZE) {
        const float ob = obias[col];
        #pragma unroll
        for (int r = 0; r < 4; ++r)
          C[(long)(rowb + r) * V_SIZE + col] = acc[mi][ni][r] + ob;
      }
    }
  }
}

// ---------------- sparse memory correction: out[b,t,v] += read*m ----------------
// grid (4 batches, 8 owner-chunks) x 64 threads: owner-per-lane
__global__ __launch_bounds__(64) void k_corr(const int* __restrict__ ids,
                                             const float* __restrict__ read_s,
                                             const float* __restrict__ decay_s,
                                             const float* __restrict__ write_s,
                                             float* __restrict__ out) {
  __shared__ int ids_s[512];
  __shared__ float rd[512], dc[512], wrs[512];
  const int b = blockIdx.x, c = blockIdx.y, l = threadIdx.x;
  for (int t = l; t < 512; t += 64) {
    int n = b * 512 + t;
    ids_s[t] = ids[n]; rd[t] = read_s[n]; dc[t] = decay_s[n]; wrs[t] = write_s[n];
  }
  __syncthreads();
  const int j = c * 64 + l;
  const int v = ids_s[j];
  for (int jj = 0; jj < j; ++jj) if (ids_s[jj] == v) return;  // not the owner
  float m = wrs[j];
  float* outb = out + (long)b * S_LEN * V_SIZE + v;
  for (int t = j + 1; t < 512; ++t) {
    outb[(long)t * V_SIZE] += rd[t] * m;
    m *= dc[t];
    if (ids_s[t] == v) m += wrs[t];
  }
}

extern "C" void kernel_launch(void* const* d_in, const int* in_sizes, int n_in,
                              void* d_out, int out_size, void* d_ws, size_t ws_size,
                              hipStream_t stream) {
  const int*   ids     = (const int*)d_in[0];
  const float* emb     = (const float*)d_in[1];
  const float* W_ih    = (const float*)d_in[2];
  const float* W_hh    = (const float*)d_in[3];
  const float* b_ih    = (const float*)d_in[4];
  const float* b_hh    = (const float*)d_in[5];
  const float* W_he    = (const float*)d_in[6];
  const float* b_he    = (const float*)d_in[7];
  const float* obias   = (const float*)d_in[8];
  const float* W_read  = (const float*)d_in[9];
  const float* b_read  = (const float*)d_in[10];
  const float* W_write = (const float*)d_in[11];
  const float* b_write = (const float*)d_in[12];
  const float* W_decay = (const float*)d_in[13];
  const float* b_decay = (const float*)d_in[14];
  const float* mscale  = (const float*)d_in[15];

  // ws: emb_bf16 (25.7MB) + proj_bf16 (1MB) + gate scalars (24KB)
  char* ws = (char*)d_ws;
  __hip_bfloat16* emb_bf  = (__hip_bfloat16*)ws;                    // V_PAD*E*2 = 25,755,648
  __hip_bfloat16* proj_bf = (__hip_bfloat16*)(ws + 25755648);       // 1,048,576
  float* read_s  = (float*)(ws + 26804224);
  float* decay_s = (float*)(ws + 26812416);
  float* write_s = (float*)(ws + 26820608);

  // scratch that dies before k_base lives inside d_out (412MB):
  char* ob = (char*)d_out;
  float* xg           = (float*)ob;                     // 12,582,912 B
  float* states       = (float*)(ob + 12582912);        //  4,194,304 B
  unsigned int* h_hist = (unsigned int*)(ob + 16777216); // 512*2048*4 = 4,194,304 B
  float* out          = (float*)d_out;

  hipMemsetAsync(h_hist, 0xFF, (size_t)S_LEN * 2048 * sizeof(unsigned int), stream);
  k_emb2bf<<<2048, 256, 0, stream>>>(emb, emb_bf);
  dim3 gxg(12, 128);
  k_xg<<<gxg, 256, 0, stream>>>(ids, emb, W_ih, b_ih, xg);
  k_scan<<<NWG, 512, 0, stream>>>(xg, W_hh, b_hh, states, h_hist);
  k_gates<<<32, 256, 0, stream>>>(states, W_read, b_read, W_write, b_write, W_decay, b_decay,
                                  mscale, read_s, decay_s, write_s);
  dim3 gpj(64, 4);
  k_proj<<<gpj, 256, 0, stream>>>(states, W_he, b_he, proj_bf);
  dim3 gb(393, 16);
  k_base<<<gb, 256, 0, stream>>>(proj_bf, emb_bf, obias, out);
  dim3 gc(4, 8);
  k_corr<<<gc, 64, 0, stream>>>(ids, read_s, decay_s, write_s, out);
}

// Round 5
// 1965.759 us; speedup vs baseline: 1.9225x; 1.1493x over previous
//
#include <hip/hip_runtime.h>
#include <hip/hip_bf16.h>
#include <hip/hip_fp16.h>
#include <math.h>

#define V_SIZE 50257
#define V_PAD  50304   // 393*128
#define E_DIM  256
#define H_DIM  512
#define G_DIM  1536
#define B_SZ   4
#define S_LEN  512

typedef __attribute__((ext_vector_type(8))) short bf16x8;
typedef __attribute__((ext_vector_type(4))) float f32x4;
typedef __attribute__((ext_vector_type(2))) _Float16 h16x2;

__device__ __forceinline__ float bf2f(unsigned short u) {
  union { unsigned int i; float f; } x; x.i = ((unsigned int)u) << 16; return x.f;
}
__device__ __forceinline__ unsigned short f2bf(float f) {
  __hip_bfloat16 h = __float2bfloat16(f);   // RNE
  return reinterpret_cast<unsigned short&>(h);
}
__device__ __forceinline__ float sigmoidf_(float x) { return 1.0f / (1.0f + expf(-x)); }
// fast variants for the scan's serial epilogue (err ~1e-7 rel, threshold is 2e-2)
__device__ __forceinline__ float fsig(float x) { return 1.0f / (1.0f + __expf(-x)); }
__device__ __forceinline__ float ftanh(float x) { return 1.0f - 2.0f / (__expf(2.0f * x) + 1.0f); }

__device__ __forceinline__ h16x2 as_h2(unsigned int u) {
  union { unsigned int u; h16x2 h; } x; x.u = u; return x.h;
}

#if defined(__has_builtin)
#if __has_builtin(__builtin_amdgcn_fdot2)
#define HAVE_FDOT2 1
#endif
#endif
__device__ __forceinline__ float fdot2_(unsigned int a, unsigned int b, float c) {
#ifdef HAVE_FDOT2
  return __builtin_amdgcn_fdot2(as_h2(a), as_h2(b), c, false);
#else
  h16x2 ha = as_h2(a), hb = as_h2(b);
  return c + (float)ha[0] * (float)hb[0] + (float)ha[1] * (float)hb[1];
#endif
}

__device__ __forceinline__ void gload_lds16(const void* g, void* l) {
  __builtin_amdgcn_global_load_lds((const __attribute__((address_space(1))) unsigned int*)g,
                                   (__attribute__((address_space(3))) unsigned int*)l, 16, 0, 0);
}

// ---------------- embedding fp32 -> bf16 (padded to V_PAD rows) ----------------
__global__ __launch_bounds__(256) void k_emb2bf(const float* __restrict__ emb,
                                                __hip_bfloat16* __restrict__ out) {
  const long total = (long)V_PAD * E_DIM;
  for (long i = (long)blockIdx.x * 256 + threadIdx.x; i < total; i += (long)gridDim.x * 256) {
    int row = (int)(i >> 8);
    float v = (row < V_SIZE) ? emb[i] : 0.0f;
    out[i] = __float2bfloat16(v);
  }
}

// ---------------- xg = emb[ids] @ W_ih^T + b_ih  (fp32) ----------------
// grid (12, 128), block 256. tile: 128 g x 16 n, K=256
__global__ __launch_bounds__(256) void k_xg(const int* __restrict__ ids, const float* __restrict__ emb,
                                            const float* __restrict__ W_ih, const float* __restrict__ b_ih,
                                            float* __restrict__ xg) {
  __shared__ float embs[16][260];
  __shared__ float wl[64][133];
  const int g0 = blockIdx.x * 128, n0 = blockIdx.y * 16, tid = threadIdx.x;
  for (int idx = tid; idx < 16 * 256; idx += 256) {
    int n = idx >> 8, e = idx & 255;
    embs[n][e] = emb[(long)ids[n0 + n] * E_DIM + e];
  }
  const int g = tid & 127, ng = tid >> 7;
  float acc[8] = {0.f,0.f,0.f,0.f,0.f,0.f,0.f,0.f};
  for (int e0 = 0; e0 < 256; e0 += 64) {
    __syncthreads();
    for (int idx = tid; idx < 128 * 64; idx += 256) {
      int r = idx >> 6, c = idx & 63;
      wl[c][r] = W_ih[(long)(g0 + r) * E_DIM + e0 + c];
    }
    __syncthreads();
    for (int c = 0; c < 64; ++c) {
      float w = wl[c][g];
      #pragma unroll
      for (int j = 0; j < 8; ++j) acc[j] += w * embs[ng * 8 + j][e0 + c];
    }
  }
  const float bias = b_ih[g0 + g];
  #pragma unroll
  for (int j = 0; j < 8; ++j) {
    int n = n0 + ng * 8 + j;
    xg[(long)n * G_DIM + g0 + g] = acc[j] + bias;
  }
}

// ---------------- persistent GRU scan: 32 wgs x 512 thr ----------------
// u64-packed data-is-the-flag protocol: h(t) published as one u64 per h-index
// (4 batches x f16) into h_hist[t][512], pre-memset to 0xFF.. (f16 of |h|<1
// can never be 0xFFFF). Each thread polls exactly ONE u64. MAC uses
// v_dot2_f32_f16 on f16-pair packed W (LDS) and h (LDS, per-wave-private
// region -> no barrier for the pair build). One __syncthreads per step.
#define NWG 32
#define WROWU 261                 // W row stride in u32 pairs (bank-spread)
#define WPLU  (16 * WROWU)
#define HROWU 260                 // hp row stride in u32 pairs
__global__ __launch_bounds__(512, 1) void k_scan(const float* __restrict__ xg,
                                                 const float* __restrict__ W_hh,
                                                 const float* __restrict__ b_hh,
                                                 float* __restrict__ states,
                                                 unsigned long long* __restrict__ h_hist) {
  __shared__ unsigned int Wp[3 * WPLU];         // 50,112 B (f16 pairs)
  __shared__ unsigned int hp[4 * HROWU];        //  4,160 B (f16 pairs, per-wave-private slices)
  __shared__ float red[2][8][16][12];           // 12,288 B double-buffered partials
  const int wg = blockIdx.x, tid = threadIdx.x;
  const int i0 = wg * 16;
  // stage W slice as f16 pairs
  for (int e = tid; e < 3 * 16 * 256; e += 512) {
    int q = e >> 12, i = (e >> 8) & 15, p = e & 255;
    float2 w2 = reinterpret_cast<const float2*>(W_hh + (long)((q << 9) + i0 + i) * H_DIM)[p];
    unsigned int pk = (unsigned int)__half_as_ushort(__float2half(w2.x)) |
                      ((unsigned int)__half_as_ushort(__float2half(w2.y)) << 16);
    Wp[q * WPLU + i * WROWU + p] = pk;
  }
  const int wave = tid >> 6, l = tid & 63, il = l >> 2, part = l & 3;
  const int ii = tid >> 2, bb = tid & 3;        // epilogue mapping (wave 0)
  const int pidx = tid >> 1;                    // pair index this thread fills
  float h_prev = 0.0f;
  float bhr = 0.f, bhz = 0.f, bhn = 0.f;
  if (tid < 64) { bhr = b_hh[i0 + ii]; bhz = b_hh[512 + i0 + ii]; bhn = b_hh[1024 + i0 + ii]; }
  __syncthreads();

  for (int t = 0; t < S_LEN; ++t) {
    // xg prefetch for the epilogue (in flight during poll+MAC)
    float xr_v = 0.f, xz_v = 0.f, xn_v = 0.f;
    if (tid < 64) {
      const float* xgrow = xg + (long)(bb * S_LEN + t) * G_DIM + i0 + ii;
      xr_v = xgrow[0]; xz_v = xgrow[512]; xn_v = xgrow[1024];
    }
    float acc[3][4] = {{0.f,0.f,0.f,0.f},{0.f,0.f,0.f,0.f},{0.f,0.f,0.f,0.f}};
    if (t > 0) {
      // one u64 poll per thread: h[0..3][hidx=tid] for step t-1
      const unsigned long long* hb = h_hist + (long)(t - 1) * 512;
      unsigned long long v;
      do {
        v = __hip_atomic_load(hb + tid, __ATOMIC_RELAXED, __HIP_MEMORY_SCOPE_AGENT);
      } while (v == 0xFFFFFFFFFFFFFFFFull);
      const unsigned int lo = (unsigned int)v, hi = (unsigned int)(v >> 32);
      const unsigned int plo = __shfl_xor(lo, 1), phi = __shfl_xor(hi, 1);
      if ((tid & 1) == 0) {       // even: build batch 0,1 pairs for (c, c+1)
        hp[pidx]         = (lo & 0xffffu) | (plo << 16);
        hp[HROWU + pidx] = (lo >> 16) | (phi & 0xffff0000u ? (plo & 0xffff0000u) : (plo & 0xffff0000u));
      } else {                    // odd: build batch 2,3 pairs
        hp[2 * HROWU + pidx] = (phi & 0xffffu) | (hi << 16);
        hp[3 * HROWU + pidx] = (phi >> 16) | (hi & 0xffff0000u);
      }
      // per-wave-private LDS region: wave-synchronous RAW, no barrier
      const int pbase = (wave << 5) + (part << 3);
      #pragma unroll
      for (int j = 0; j < 8; ++j) {
        const int p = pbase + j;
        const unsigned int w_r = Wp[il * WROWU + p];
        const unsigned int w_z = Wp[WPLU + il * WROWU + p];
        const unsigned int w_n = Wp[2 * WPLU + il * WROWU + p];
        const unsigned int h0 = hp[p];
        const unsigned int h1 = hp[HROWU + p];
        const unsigned int h2 = hp[2 * HROWU + p];
        const unsigned int h3 = hp[3 * HROWU + p];
        acc[0][0] = fdot2_(w_r, h0, acc[0][0]); acc[0][1] = fdot2_(w_r, h1, acc[0][1]);
        acc[0][2] = fdot2_(w_r, h2, acc[0][2]); acc[0][3] = fdot2_(w_r, h3, acc[0][3]);
        acc[1][0] = fdot2_(w_z, h0, acc[1][0]); acc[1][1] = fdot2_(w_z, h1, acc[1][1]);
        acc[1][2] = fdot2_(w_z, h2, acc[1][2]); acc[1][3] = fdot2_(w_z, h3, acc[1][3]);
        acc[2][0] = fdot2_(w_n, h0, acc[2][0]); acc[2][1] = fdot2_(w_n, h1, acc[2][1]);
        acc[2][2] = fdot2_(w_n, h2, acc[2][2]); acc[2][3] = fdot2_(w_n, h3, acc[2][3]);
      }
    }
    // reduce over 'part' (4 lanes), stash per-wave partials
    #pragma unroll
    for (int q = 0; q < 3; ++q)
      #pragma unroll
      for (int b = 0; b < 4; ++b) {
        float v = acc[q][b];
        v += __shfl_xor(v, 1);
        v += __shfl_xor(v, 2);
        if (part == 0) red[t & 1][wave][il][q * 4 + b] = v;
      }
    __syncthreads();                             // the ONE barrier per step
    if (tid < 64) {
      float hr = bhr, hz = bhz, hn = bhn;
      #pragma unroll
      for (int w = 0; w < 8; ++w) {
        hr += red[t & 1][w][ii][0 + bb];
        hz += red[t & 1][w][ii][4 + bb];
        hn += red[t & 1][w][ii][8 + bb];
      }
      float r  = fsig(xr_v + hr);
      float z  = fsig(xz_v + hz);
      float nn = ftanh(xn_v + r * hn);
      float h_new = (1.0f - z) * nn + z * h_prev;
      h_prev = h_new;
      // publish FIRST (critical path), states store after
      unsigned int hu = (unsigned int)__half_as_ushort(__float2half(h_new));
      unsigned int v1 = __shfl_down(hu, 1);
      unsigned int v2 = __shfl_down(hu, 2);
      unsigned int v3 = __shfl_down(hu, 3);
      if (bb == 0) {
        unsigned long long pk = (unsigned long long)(hu | (v1 << 16)) |
                                ((unsigned long long)(v2 | (v3 << 16)) << 32);
        __hip_atomic_store(h_hist + (long)t * 512 + i0 + ii, pk,
                           __ATOMIC_RELAXED, __HIP_MEMORY_SCOPE_AGENT);
      }
      states[(long)(bb * S_LEN + t) * H_DIM + i0 + ii] = h_new;
    }
    // no trailing barrier: hp per-wave-private, red double-buffered
  }
}

// ---------------- read/decay/write gates (wave-per-row, coalesced) ----------------
__global__ __launch_bounds__(256) void k_gates(const float* __restrict__ states,
     const float* __restrict__ W_read, const float* __restrict__ b_read,
     const float* __restrict__ W_write, const float* __restrict__ b_write,
     const float* __restrict__ W_decay, const float* __restrict__ b_decay,
     const float* __restrict__ mscale,
     float* __restrict__ read_s, float* __restrict__ decay_s, float* __restrict__ write_s) {
  __shared__ float wr[512], ww[512], wd[512];
  const int tid = threadIdx.x;
  for (int i = tid; i < 512; i += 256) { wr[i] = W_read[i]; ww[i] = W_write[i]; wd[i] = W_decay[i]; }
  __syncthreads();
  const int wave = tid >> 6, l = tid & 63;
  const float br = b_read[0], bw = b_write[0], bd = b_decay[0], ms = mscale[0];
  for (int r = 0; r < 16; ++r) {
    const int n = blockIdx.x * 64 + wave * 16 + r;
    const float* st = states + (long)n * H_DIM;
    float ar = 0.f, aw = 0.f, ad = 0.f;
    #pragma unroll
    for (int h0 = 0; h0 < 512; h0 += 64) {
      float s = st[h0 + l];
      ar += s * wr[h0 + l]; aw += s * ww[h0 + l]; ad += s * wd[h0 + l];
    }
    #pragma unroll
    for (int k = 1; k < 64; k <<= 1) {
      ar += __shfl_xor(ar, k); aw += __shfl_xor(aw, k); ad += __shfl_xor(ad, k);
    }
    if (l == 0) {
      read_s[n]  = sigmoidf_(ar + br) * ms;
      write_s[n] = sigmoidf_(aw + bw);
      decay_s[n] = sigmoidf_(ad + bd);
    }
  }
}

// ---------------- proj = states @ W_he^T + b_he -> bf16 ----------------
__global__ __launch_bounds__(256) void k_proj(const float* __restrict__ states,
                                              const float* __restrict__ W_he,
                                              const float* __restrict__ b_he,
                                              __hip_bfloat16* __restrict__ proj) {
  __shared__ float sts[32][64];
  __shared__ float wle[64][69];
  const int n0 = blockIdx.x * 32, e0 = blockIdx.y * 64, tid = threadIdx.x;
  const int e = tid & 63, ng = tid >> 6;
  float acc[8] = {0.f,0.f,0.f,0.f,0.f,0.f,0.f,0.f};
  for (int h0 = 0; h0 < 512; h0 += 64) {
    __syncthreads();
    for (int idx = tid; idx < 32 * 64; idx += 256) {
      int n = idx >> 6, c = idx & 63;
      sts[n][c] = states[(long)(n0 + n) * H_DIM + h0 + c];
    }
    for (int idx = tid; idx < 64 * 64; idx += 256) {
      int r = idx >> 6, c = idx & 63;
      wle[c][r] = W_he[(long)(e0 + r) * H_DIM + h0 + c];
    }
    __syncthreads();
    for (int c = 0; c < 64; ++c) {
      float w = wle[c][e];
      #pragma unroll
      for (int j = 0; j < 8; ++j) acc[j] += w * sts[ng * 8 + j][c];
    }
  }
  const float bias = b_he[e0 + e];
  #pragma unroll
  for (int j = 0; j < 8; ++j) {
    int n = n0 + ng * 8 + j;
    proj[(long)n * E_DIM + e0 + e] = __float2bfloat16(acc[j] + bias);
  }
}

// ---------------- base = proj @ emb^T + output_bias (bf16 MFMA) ----------------
// grid (393, 16), block 256 (4 waves 2x2), tile 128x128, BK=32, K=256
__global__ __launch_bounds__(256) void k_base(const __hip_bfloat16* __restrict__ A,
                                              const __hip_bfloat16* __restrict__ Bm,
                                              const float* __restrict__ obias,
                                              float* __restrict__ C) {
  __shared__ unsigned short As[128 * 32], Bs[128 * 32];
  const int n0 = blockIdx.x * 128, m0 = blockIdx.y * 128, tid = threadIdx.x;
  const int wid = tid >> 6, l = tid & 63;
  const int wm = wid >> 1, wn = wid & 1;
  f32x4 acc[4][4];
  #pragma unroll
  for (int mi = 0; mi < 4; ++mi)
    #pragma unroll
    for (int ni = 0; ni < 4; ++ni) acc[mi][ni] = (f32x4){0.f, 0.f, 0.f, 0.f};

  for (int kk = 0; kk < 256; kk += 32) {
    __syncthreads();
    #pragma unroll
    for (int s = 0; s < 2; ++s) {
      const int cibase = wid * 128 + s * 64;
      const int ci = cibase + l;
      const int row = ci >> 2, cq = ci & 3;
      gload_lds16(A + (long)(m0 + row) * E_DIM + kk + cq * 8, As + cibase * 8);
      gload_lds16(Bm + (long)(n0 + row) * E_DIM + kk + cq * 8, Bs + cibase * 8);
    }
    __syncthreads();
    bf16x8 af[4], bfr[4];
    const int krow = (l >> 4) * 8;
    #pragma unroll
    for (int mi = 0; mi < 4; ++mi) {
      int row = wm * 64 + mi * 16 + (l & 15);
      af[mi] = *reinterpret_cast<const bf16x8*>(&As[row * 32 + krow]);
    }
    #pragma unroll
    for (int ni = 0; ni < 4; ++ni) {
      int row = wn * 64 + ni * 16 + (l & 15);
      bfr[ni] = *reinterpret_cast<const bf16x8*>(&Bs[row * 32 + krow]);
    }
    #pragma unroll
    for (int mi = 0; mi < 4; ++mi)
      #pragma unroll
      for (int ni = 0; ni < 4; ++ni)
        acc[mi][ni] = __builtin_amdgcn_mfma_f32_16x16x32_bf16(af[mi], bfr[ni], acc[mi][ni], 0, 0, 0);
  }
  #pragma unroll
  for (int mi = 0; mi < 4; ++mi) {
    const int rowb = m0 + wm * 64 + mi * 16 + (l >> 4) * 4;
    #pragma unroll
    for (int ni = 0; ni < 4; ++ni) {
      const int col = n0 + wn * 64 + ni * 16 + (l & 15);
      if (col < V_SIZE) {
        const float ob = obias[col];
        #pragma unroll
        for (int r = 0; r < 4; ++r)
          C[(long)(rowb + r) * V_SIZE + col] = acc[mi][ni][r] + ob;
      }
    }
  }
}

// ---------------- sparse memory correction: out[b,t,v] += read*m ----------------
// grid (4 batches, 8 owner-chunks) x 64 threads: owner-per-lane
__global__ __launch_bounds__(64) void k_corr(const int* __restrict__ ids,
                                             const float* __restrict__ read_s,
                                             const float* __restrict__ decay_s,
                                             const float* __restrict__ write_s,
                                             float* __restrict__ out) {
  __shared__ int ids_s[512];
  __shared__ float rd[512], dc[512], wrs[512];
  const int b = blockIdx.x, c = blockIdx.y, l = threadIdx.x;
  for (int t = l; t < 512; t += 64) {
    int n = b * 512 + t;
    ids_s[t] = ids[n]; rd[t] = read_s[n]; dc[t] = decay_s[n]; wrs[t] = write_s[n];
  }
  __syncthreads();
  const int j = c * 64 + l;
  const int v = ids_s[j];
  for (int jj = 0; jj < j; ++jj) if (ids_s[jj] == v) return;  // not the owner
  float m = wrs[j];
  float* outb = out + (long)b * S_LEN * V_SIZE + v;
  for (int t = j + 1; t < 512; ++t) {
    outb[(long)t * V_SIZE] += rd[t] * m;
    m *= dc[t];
    if (ids_s[t] == v) m += wrs[t];
  }
}

extern "C" void kernel_launch(void* const* d_in, const int* in_sizes, int n_in,
                              void* d_out, int out_size, void* d_ws, size_t ws_size,
                              hipStream_t stream) {
  const int*   ids     = (const int*)d_in[0];
  const float* emb     = (const float*)d_in[1];
  const float* W_ih    = (const float*)d_in[2];
  const float* W_hh    = (const float*)d_in[3];
  const float* b_ih    = (const float*)d_in[4];
  const float* b_hh    = (const float*)d_in[5];
  const float* W_he    = (const float*)d_in[6];
  const float* b_he    = (const float*)d_in[7];
  const float* obias   = (const float*)d_in[8];
  const float* W_read  = (const float*)d_in[9];
  const float* b_read  = (const float*)d_in[10];
  const float* W_write = (const float*)d_in[11];
  const float* b_write = (const float*)d_in[12];
  const float* W_decay = (const float*)d_in[13];
  const float* b_decay = (const float*)d_in[14];
  const float* mscale  = (const float*)d_in[15];

  // ws: emb_bf16 (25.7MB) + proj_bf16 (1MB) + gate scalars (24KB)
  char* ws = (char*)d_ws;
  __hip_bfloat16* emb_bf  = (__hip_bfloat16*)ws;                    // V_PAD*E*2 = 25,755,648
  __hip_bfloat16* proj_bf = (__hip_bfloat16*)(ws + 25755648);       // 1,048,576
  float* read_s  = (float*)(ws + 26804224);
  float* decay_s = (float*)(ws + 26812416);
  float* write_s = (float*)(ws + 26820608);

  // scratch that dies before k_base lives inside d_out (412MB):
  char* ob = (char*)d_out;
  float* xg  = (float*)ob;                                   // 12,582,912 B
  float* states = (float*)(ob + 12582912);                   //  4,194,304 B
  unsigned long long* h_hist = (unsigned long long*)(ob + 16777216); // 512*512*8 = 2,097,152 B
  float* out = (float*)d_out;

  hipMemsetAsync(h_hist, 0xFF, (size_t)S_LEN * 512 * sizeof(unsigned long long), stream);
  k_emb2bf<<<2048, 256, 0, stream>>>(emb, emb_bf);
  dim3 gxg(12, 128);
  k_xg<<<gxg, 256, 0, stream>>>(ids, emb, W_ih, b_ih, xg);
  k_scan<<<NWG, 512, 0, stream>>>(xg, W_hh, b_hh, states, h_hist);
  k_gates<<<32, 256, 0, stream>>>(states, W_read, b_read, W_write, b_write, W_decay, b_decay,
                                  mscale, read_s, decay_s, write_s);
  dim3 gpj(64, 4);
  k_proj<<<gpj, 256, 0, stream>>>(states, W_he, b_he, proj_bf);
  dim3 gb(393, 16);
  k_base<<<gb, 256, 0, stream>>>(proj_bf, emb_bf, obias, out);
  dim3 gc(4, 8);
  k_corr<<<gc, 64, 0, stream>>>(ids, read_s, decay_s, write_s, out);
}